// Round 1
// baseline (434.504 us; speedup 1.0000x reference)
//
#include <hip/hip_runtime.h>
#include <math.h>

#define TWO_PI_F 6.283185307179586f

// Problem dims (fixed by setup_inputs)
constexpr int B   = 8;
constexpr int NIN = 128;
constexpr int NK  = 5;

// Workspace layout (in floats)
// data GM (conv input / topk output): max B*Ci*Nd = 8*8*32 = 2048 comps
constexpr size_t OFF_DW  = 0;         // 2048
constexpr size_t OFF_DP  = 2048;      // 4096  (2 per comp)
constexpr size_t OFF_DC  = 6144;      // 6144  (3 per comp, symmetric 2x2)
// conv output: max B*Co*N = 8*16*1280 = 163840 comps
constexpr size_t OFF_CW  = 12288;     // 163840
constexpr size_t OFF_CP  = 176128;    // 327680
constexpr size_t OFF_CC  = 503808;    // 491520
constexpr size_t OFF_CWN = 995328;    // 163840 (relu-fitted weights)
constexpr size_t OFF_X   = 1159168;   // 80 (pre-BN class scores)
// total 1159248 floats = 4.64 MB

// ---------------- norm0: per-sample CovScaleNorm + WeightBatchNorm ----------
__global__ void norm0_kernel(const float* __restrict__ in_w,
                             const float* __restrict__ in_p,
                             const float* __restrict__ in_c,
                             float* __restrict__ dw, float* __restrict__ dp,
                             float* __restrict__ dc) {
    int b = blockIdx.x;           // 8 blocks
    int t = threadIdx.x;          // 128 threads, one comp each
    __shared__ float red[128];
    int idx = b * NIN + t;
    float w  = in_w[idx];
    float p0 = in_p[2 * idx], p1 = in_p[2 * idx + 1];
    float c00 = in_c[4 * idx], c01 = in_c[4 * idx + 1], c11 = in_c[4 * idx + 3];

    red[t] = 0.5f * (c00 + c11);               // trace/D
    __syncthreads();
    for (int s = 64; s > 0; s >>= 1) { if (t < s) red[t] += red[t + s]; __syncthreads(); }
    float f = rsqrtf(red[0] / NIN + 1e-8f);
    __syncthreads();

    float f2 = f * f;
    p0 *= f; p1 *= f; c00 *= f2; c01 *= f2; c11 *= f2;
    float det = c00 * c11 - c01 * c01;
    float integ = w * TWO_PI_F * sqrtf(fmaxf(det, 1e-12f));
    red[t] = fabsf(integ);
    __syncthreads();
    for (int s = 64; s > 0; s >>= 1) { if (t < s) red[t] += red[t + s]; __syncthreads(); }
    float scale = red[0] / NIN + 1e-6f;

    w /= scale;
    dw[idx] = w;
    dp[2 * idx] = p0; dp[2 * idx + 1] = p1;
    dc[3 * idx] = c00; dc[3 * idx + 1] = c01; dc[3 * idx + 2] = c11;
}

// ---------------- gm_convolve: one thread per output component --------------
__global__ void conv_kernel(const float* __restrict__ dw, const float* __restrict__ dp,
                            const float* __restrict__ dc,
                            const float* __restrict__ kw, const float* __restrict__ kp,
                            const float* __restrict__ kc,
                            float* __restrict__ cw, float* __restrict__ cp,
                            float* __restrict__ cc,
                            int Co, int Ci, int Nd, int total) {
    int t = blockIdx.x * blockDim.x + threadIdx.x;
    if (t >= total) return;
    int N  = Ci * Nd * NK;
    int n  = t % N;
    int bc = t / N;
    int co = bc % Co;
    int b  = bc / Co;
    int ci  = n / (Nd * NK);
    int rem = n % (Nd * NK);
    int nd  = rem / NK;
    int nk  = rem % NK;
    int di = (b * Ci + ci) * Nd + nd;
    int ki = (co * Ci + ci) * NK + nk;

    float wd = dw[di], pd0 = dp[2 * di], pd1 = dp[2 * di + 1];
    float d00 = dc[3 * di], d01 = dc[3 * di + 1], d11 = dc[3 * di + 2];
    float wk = kw[ki], pk0 = kp[2 * ki], pk1 = kp[2 * ki + 1];
    float k00 = kc[4 * ki], k01 = kc[4 * ki + 1], k11 = kc[4 * ki + 3];

    float s00 = d00 + k00, s01 = d01 + k01, s11 = d11 + k11;
    float det_d = d00 * d11 - d01 * d01;
    float det_k = k00 * k11 - k01 * k01;
    float det_s = s00 * s11 - s01 * s01;
    float amp = TWO_PI_F * sqrtf(fmaxf(det_d * det_k / fmaxf(det_s, 1e-12f), 1e-20f));

    cw[t] = wd * wk * amp;
    cp[2 * t] = pd0 + pk0; cp[2 * t + 1] = pd1 + pk1;
    cc[3 * t] = s00; cc[3 * t + 1] = s01; cc[3 * t + 2] = s11;
}

// ------------- gm_eval_at_centers + relu scaling (w_new) --------------------
// block = (b*L + l, i-tile). Entire j-set staged in LDS (N <= 1280).
__global__ __launch_bounds__(256) void eval_kernel(
        const float* __restrict__ cw, const float* __restrict__ cp,
        const float* __restrict__ cc, float* __restrict__ cwn,
        int N, int tiles) {
    __shared__ float sw[1280], sp0[1280], sp1[1280];
    __shared__ float sP00[1280], sP01[1280], sP11[1280];
    int blk  = blockIdx.x;
    int tile = blk % tiles;
    int bl   = blk / tiles;
    size_t base = (size_t)bl * N;

    for (int j = threadIdx.x; j < N; j += 256) {
        size_t o = base + j;
        float c00 = cc[3 * o], c01 = cc[3 * o + 1], c11 = cc[3 * o + 2];
        float inv = 1.0f / (c00 * c11 - c01 * c01);
        sP00[j] = c11 * inv; sP01[j] = -c01 * inv; sP11[j] = c00 * inv;
        sw[j] = cw[o]; sp0[j] = cp[2 * o]; sp1[j] = cp[2 * o + 1];
    }
    __syncthreads();

    int i = tile * 256 + threadIdx.x;
    if (i >= N) return;
    float pi0 = sp0[i], pi1 = sp1[i];
    float s = 0.f;
    for (int j = 0; j < N; ++j) {
        float d0 = pi0 - sp0[j];
        float d1 = pi1 - sp1[j];
        float q = d0 * d0 * sP00[j] + 2.f * d0 * d1 * sP01[j] + d1 * d1 * sP11[j];
        s += sw[j] * __expf(-0.5f * q);
    }
    float w = sw[i];
    float denom = (fabsf(s) > 1e-6f) ? s : 1e-6f;
    cwn[base + i] = w * (fmaxf(s, 0.f) / denom);
}

// ------------- top-k by |w_new|*sqrt(det C) + gather into data layout -------
__global__ void topk_kernel(const float* __restrict__ cwn, const float* __restrict__ cp,
                            const float* __restrict__ cc,
                            float* __restrict__ dw, float* __restrict__ dp,
                            float* __restrict__ dc,
                            int N, int K) {
    __shared__ float sc[1280];
    __shared__ float rv[256];
    __shared__ int   ri[256];
    __shared__ int   sel[32];
    int bl = blockIdx.x;          // b*L + l
    size_t base = (size_t)bl * N;
    int t = threadIdx.x;

    for (int j = t; j < N; j += 256) {
        size_t o = base + j;
        float c00 = cc[3 * o], c01 = cc[3 * o + 1], c11 = cc[3 * o + 2];
        float det = c00 * c11 - c01 * c01;
        sc[j] = fabsf(cwn[o]) * sqrtf(fmaxf(det, 1e-12f));
    }
    __syncthreads();

    for (int r = 0; r < K; ++r) {
        float bv = -INFINITY; int bi = N;
        for (int j = t; j < N; j += 256) {
            float v = sc[j];
            if (v > bv) { bv = v; bi = j; }   // ascending j => lowest idx on tie
        }
        rv[t] = bv; ri[t] = bi;
        __syncthreads();
        for (int s = 128; s > 0; s >>= 1) {
            if (t < s) {
                if (rv[t + s] > rv[t] || (rv[t + s] == rv[t] && ri[t + s] < ri[t])) {
                    rv[t] = rv[t + s]; ri[t] = ri[t + s];
                }
            }
            __syncthreads();
        }
        if (t == 0) { sel[r] = ri[0]; sc[ri[0]] = -INFINITY; }
        __syncthreads();
    }

    if (t < K) {
        size_t j = base + sel[t];
        int o = bl * K + t;       // next-layer data layout [B, Ci=L, K]
        dw[o] = cwn[j];
        dp[2 * o] = cp[2 * j]; dp[2 * o + 1] = cp[2 * j + 1];
        dc[3 * o] = cc[3 * j]; dc[3 * o + 1] = cc[3 * j + 1]; dc[3 * o + 2] = cc[3 * j + 2];
    }
}

// ------- per-channel CovScaleNorm + WeightBatchNorm (batch_norm=True) -------
__global__ void norm_kernel(float* __restrict__ dw, float* __restrict__ dp,
                            float* __restrict__ dc, int L, int K) {
    int l = blockIdx.x;           // one block per channel
    int t = threadIdx.x;          // 256
    __shared__ float red[256];
    int M = B * K;

    float tsum = 0.f;
    for (int u = t; u < M; u += 256) {
        int b = u / K, r = u % K;
        int idx = (b * L + l) * K + r;
        tsum += 0.5f * (dc[3 * idx] + dc[3 * idx + 2]);
    }
    red[t] = tsum; __syncthreads();
    for (int s = 128; s > 0; s >>= 1) { if (t < s) red[t] += red[t + s]; __syncthreads(); }
    float f = rsqrtf(red[0] / M + 1e-8f);
    __syncthreads();

    float f2 = f * f;
    float asum = 0.f;
    for (int u = t; u < M; u += 256) {
        int b = u / K, r = u % K;
        int idx = (b * L + l) * K + r;
        float c00 = dc[3 * idx] * f2, c01 = dc[3 * idx + 1] * f2, c11 = dc[3 * idx + 2] * f2;
        dc[3 * idx] = c00; dc[3 * idx + 1] = c01; dc[3 * idx + 2] = c11;
        dp[2 * idx] *= f; dp[2 * idx + 1] *= f;
        float det = c00 * c11 - c01 * c01;
        asum += fabsf(dw[idx] * TWO_PI_F * sqrtf(fmaxf(det, 1e-12f)));
    }
    red[t] = asum; __syncthreads();
    for (int s = 128; s > 0; s >>= 1) { if (t < s) red[t] += red[t + s]; __syncthreads(); }
    float scale = red[0] / M + 1e-6f;
    __syncthreads();

    for (int u = t; u < M; u += 256) {
        int b = u / K, r = u % K;
        dw[(b * L + l) * K + r] /= scale;
    }
}

// ---- layer-2 norm + integrate fused (no top-k; w-norm is linear in w) ------
__global__ void final_layer_kernel(const float* __restrict__ cwn,
                                   const float* __restrict__ cc,
                                   float* __restrict__ xbuf, int L, int N) {
    int co = blockIdx.x;          // 10 blocks
    int t  = threadIdx.x;         // 256
    __shared__ float red[256];
    int M = B * N;

    float tsum = 0.f;
    for (int b = 0; b < B; ++b) {
        size_t base = (size_t)(b * L + co) * N;
        for (int n = t; n < N; n += 256)
            tsum += 0.5f * (cc[3 * (base + n)] + cc[3 * (base + n) + 2]);
    }
    red[t] = tsum; __syncthreads();
    for (int s = 128; s > 0; s >>= 1) { if (t < s) red[t] += red[t + s]; __syncthreads(); }
    float f = rsqrtf(red[0] / M + 1e-8f);
    __syncthreads();

    float f4 = f * f * f * f;
    float asum = 0.f;
    float bsums[B];
#pragma unroll
    for (int b = 0; b < B; ++b) {
        size_t base = (size_t)(b * L + co) * N;
        float ssum = 0.f;
        for (int n = t; n < N; n += 256) {
            float c00 = cc[3 * (base + n)], c01 = cc[3 * (base + n) + 1],
                  c11 = cc[3 * (base + n) + 2];
            float det = (c00 * c11 - c01 * c01) * f4;
            float integ = cwn[base + n] * TWO_PI_F * sqrtf(fmaxf(det, 1e-12f));
            asum += fabsf(integ);
            ssum += integ;
        }
        bsums[b] = ssum;
    }
    red[t] = asum; __syncthreads();
    for (int s = 128; s > 0; s >>= 1) { if (t < s) red[t] += red[t + s]; __syncthreads(); }
    float scale = red[0] / M + 1e-6f;
    __syncthreads();

    for (int b = 0; b < B; ++b) {
        red[t] = bsums[b]; __syncthreads();
        for (int s = 128; s > 0; s >>= 1) { if (t < s) red[t] += red[t + s]; __syncthreads(); }
        if (t == 0) xbuf[b * L + co] = red[0] / scale;
        __syncthreads();
    }
}

// ---------------- final BatchNorm1d (training) + log_softmax ----------------
__global__ void final_bn_kernel(const float* __restrict__ xbuf, float* __restrict__ out) {
    __shared__ float xs[80];
    __shared__ float xn[80];
    int t = threadIdx.x;
    if (t < 80) xs[t] = xbuf[t];
    __syncthreads();
    if (t < 10) {
        float mu = 0.f;
        for (int b = 0; b < 8; ++b) mu += xs[b * 10 + t];
        mu *= 0.125f;
        float var = 0.f;
        for (int b = 0; b < 8; ++b) { float d = xs[b * 10 + t] - mu; var += d * d; }
        var *= 0.125f;
        float inv = rsqrtf(var + 1e-5f);
        for (int b = 0; b < 8; ++b) xn[b * 10 + t] = (xs[b * 10 + t] - mu) * inv;
    }
    __syncthreads();
    if (t < 8) {
        float mx = -INFINITY;
        for (int c = 0; c < 10; ++c) mx = fmaxf(mx, xn[t * 10 + c]);
        float se = 0.f;
        for (int c = 0; c < 10; ++c) se += expf(xn[t * 10 + c] - mx);
        float lse = mx + logf(se);
        for (int c = 0; c < 10; ++c) out[t * 10 + c] = xn[t * 10 + c] - lse;
    }
}

extern "C" void kernel_launch(void* const* d_in, const int* in_sizes, int n_in,
                              void* d_out, int out_size, void* d_ws, size_t ws_size,
                              hipStream_t stream) {
    const float* in_w = (const float*)d_in[0];
    const float* in_p = (const float*)d_in[1];
    const float* in_c = (const float*)d_in[2];
    const float* k0w = (const float*)d_in[3];
    const float* k0p = (const float*)d_in[4];
    const float* k0c = (const float*)d_in[5];
    const float* k1w = (const float*)d_in[6];
    const float* k1p = (const float*)d_in[7];
    const float* k1c = (const float*)d_in[8];
    const float* k2w = (const float*)d_in[9];
    const float* k2p = (const float*)d_in[10];
    const float* k2c = (const float*)d_in[11];

    float* ws  = (float*)d_ws;
    float* dw  = ws + OFF_DW;
    float* dp  = ws + OFF_DP;
    float* dc  = ws + OFF_DC;
    float* cw  = ws + OFF_CW;
    float* cp  = ws + OFF_CP;
    float* cc  = ws + OFF_CC;
    float* cwn = ws + OFF_CWN;
    float* xb  = ws + OFF_X;
    float* out = (float*)d_out;

    // norm0 (per-sample stats)
    norm0_kernel<<<B, 128, 0, stream>>>(in_w, in_p, in_c, dw, dp, dc);

    // ---- layer 0: Ci=1, Co=8, Nd=128, N=640, n_fit=32 ----
    {
        int Co = 8, Ci = 1, Nd = 128, N = Ci * Nd * NK;   // 640
        int total = B * Co * N;                            // 40960
        int tiles = (N + 255) / 256;                       // 3
        conv_kernel<<<(total + 255) / 256, 256, 0, stream>>>(dw, dp, dc, k0w, k0p, k0c,
                                                             cw, cp, cc, Co, Ci, Nd, total);
        eval_kernel<<<B * Co * tiles, 256, 0, stream>>>(cw, cp, cc, cwn, N, tiles);
        topk_kernel<<<B * Co, 256, 0, stream>>>(cwn, cp, cc, dw, dp, dc, N, 32);
        norm_kernel<<<Co, 256, 0, stream>>>(dw, dp, dc, Co, 32);
    }
    // ---- layer 1: Ci=8, Co=16, Nd=32, N=1280, n_fit=16 ----
    {
        int Co = 16, Ci = 8, Nd = 32, N = Ci * Nd * NK;    // 1280
        int total = B * Co * N;                            // 163840
        int tiles = (N + 255) / 256;                       // 5
        conv_kernel<<<(total + 255) / 256, 256, 0, stream>>>(dw, dp, dc, k1w, k1p, k1c,
                                                             cw, cp, cc, Co, Ci, Nd, total);
        eval_kernel<<<B * Co * tiles, 256, 0, stream>>>(cw, cp, cc, cwn, N, tiles);
        topk_kernel<<<B * Co, 256, 0, stream>>>(cwn, cp, cc, dw, dp, dc, N, 16);
        norm_kernel<<<Co, 256, 0, stream>>>(dw, dp, dc, Co, 16);
    }
    // ---- layer 2: Ci=16, Co=10, Nd=16, N=1280, keep all ----
    {
        int Co = 10, Ci = 16, Nd = 16, N = Ci * Nd * NK;   // 1280
        int total = B * Co * N;                            // 102400
        int tiles = (N + 255) / 256;                       // 5
        conv_kernel<<<(total + 255) / 256, 256, 0, stream>>>(dw, dp, dc, k2w, k2p, k2c,
                                                             cw, cp, cc, Co, Ci, Nd, total);
        eval_kernel<<<B * Co * tiles, 256, 0, stream>>>(cw, cp, cc, cwn, N, tiles);
        final_layer_kernel<<<Co, 256, 0, stream>>>(cwn, cc, xb, Co, N);
    }
    // final BN + log_softmax
    final_bn_kernel<<<1, 128, 0, stream>>>(xb, out);
}

// Round 2
// 337.481 us; speedup vs baseline: 1.2875x; 1.2875x over previous
//
#include <hip/hip_runtime.h>
#include <math.h>

#define TWO_PI_F 6.283185307179586f

// Problem dims (fixed by setup_inputs)
constexpr int B   = 8;
constexpr int NIN = 128;
constexpr int NK  = 5;

// Workspace layout (in floats)
constexpr size_t OFF_DW  = 0;         // 2048
constexpr size_t OFF_DP  = 2048;      // 4096  (2 per comp)
constexpr size_t OFF_DC  = 6144;      // 6144  (3 per comp, symmetric 2x2)
constexpr size_t OFF_CW  = 12288;     // 163840
constexpr size_t OFF_CP  = 176128;    // 327680
constexpr size_t OFF_CC  = 503808;    // 491520
constexpr size_t OFF_PART = 995328;   // JS * 163840 partial sums (JS from ws_size)
constexpr size_t BLN_MAX  = 163840;   // max bl_count * N over layers

// ---------------- norm0: per-sample CovScaleNorm + WeightBatchNorm ----------
__global__ void norm0_kernel(const float* __restrict__ in_w,
                             const float* __restrict__ in_p,
                             const float* __restrict__ in_c,
                             float* __restrict__ dw, float* __restrict__ dp,
                             float* __restrict__ dc) {
    int b = blockIdx.x;           // 8 blocks
    int t = threadIdx.x;          // 128 threads, one comp each
    __shared__ float red[128];
    int idx = b * NIN + t;
    float w  = in_w[idx];
    float p0 = in_p[2 * idx], p1 = in_p[2 * idx + 1];
    float c00 = in_c[4 * idx], c01 = in_c[4 * idx + 1], c11 = in_c[4 * idx + 3];

    red[t] = 0.5f * (c00 + c11);               // trace/D
    __syncthreads();
    for (int s = 64; s > 0; s >>= 1) { if (t < s) red[t] += red[t + s]; __syncthreads(); }
    float f = rsqrtf(red[0] / NIN + 1e-8f);
    __syncthreads();

    float f2 = f * f;
    p0 *= f; p1 *= f; c00 *= f2; c01 *= f2; c11 *= f2;
    float det = c00 * c11 - c01 * c01;
    float integ = w * TWO_PI_F * sqrtf(fmaxf(det, 1e-12f));
    red[t] = fabsf(integ);
    __syncthreads();
    for (int s = 64; s > 0; s >>= 1) { if (t < s) red[t] += red[t + s]; __syncthreads(); }
    float scale = red[0] / NIN + 1e-6f;

    w /= scale;
    dw[idx] = w;
    dp[2 * idx] = p0; dp[2 * idx + 1] = p1;
    dc[3 * idx] = c00; dc[3 * idx + 1] = c01; dc[3 * idx + 2] = c11;
}

// ---------------- gm_convolve: one thread per output component --------------
__global__ void conv_kernel(const float* __restrict__ dw, const float* __restrict__ dp,
                            const float* __restrict__ dc,
                            const float* __restrict__ kw, const float* __restrict__ kp,
                            const float* __restrict__ kc,
                            float* __restrict__ cw, float* __restrict__ cp,
                            float* __restrict__ cc,
                            int Co, int Ci, int Nd, int total) {
    int t = blockIdx.x * blockDim.x + threadIdx.x;
    if (t >= total) return;
    int N  = Ci * Nd * NK;
    int n  = t % N;
    int bc = t / N;
    int co = bc % Co;
    int b  = bc / Co;
    int ci  = n / (Nd * NK);
    int rem = n % (Nd * NK);
    int nd  = rem / NK;
    int nk  = rem % NK;
    int di = (b * Ci + ci) * Nd + nd;
    int ki = (co * Ci + ci) * NK + nk;

    float wd = dw[di], pd0 = dp[2 * di], pd1 = dp[2 * di + 1];
    float d00 = dc[3 * di], d01 = dc[3 * di + 1], d11 = dc[3 * di + 2];
    float wk = kw[ki], pk0 = kp[2 * ki], pk1 = kp[2 * ki + 1];
    float k00 = kc[4 * ki], k01 = kc[4 * ki + 1], k11 = kc[4 * ki + 3];

    float s00 = d00 + k00, s01 = d01 + k01, s11 = d11 + k11;
    float det_d = d00 * d11 - d01 * d01;
    float det_k = k00 * k11 - k01 * k01;
    float det_s = s00 * s11 - s01 * s01;
    float amp = TWO_PI_F * sqrtf(fmaxf(det_d * det_k / fmaxf(det_s, 1e-12f), 1e-20f));

    cw[t] = wd * wk * amp;
    cp[2 * t] = pd0 + pk0; cp[2 * t + 1] = pd1 + pk1;
    cc[3 * t] = s00; cc[3 * t + 1] = s01; cc[3 * t + 2] = s11;
}

// ------------- gm_eval_at_centers: partial sums over a j-chunk --------------
// grid = bl_count * tiles * JS; block 256 threads, each owning 2 i's.
// LDS: packed float4 {p0,p1,A00,A01h} and {A11,w,-,-} with A = -0.5*log2e*inv(C).
__global__ __launch_bounds__(256) void eval_kernel(
        const float* __restrict__ cw, const float* __restrict__ cp,
        const float* __restrict__ cc, float* __restrict__ part,
        int N, int tiles, int JS, int chunk, int BLN) {
    extern __shared__ float4 sm[];
    float4* sA = sm;
    float4* sB = sm + chunk;
    int blk = blockIdx.x;
    int js   = blk % JS;
    int tile = (blk / JS) % tiles;
    int bl   = blk / (JS * tiles);
    int j0 = js * chunk;
    int cnt = min(chunk, N - j0);
    size_t base = (size_t)bl * N;
    const float NHL2E = -0.72134752044448f;   // -0.5 * log2(e)
    const float2* cp2 = (const float2*)cp;

    for (int j = threadIdx.x; j < cnt; j += 256) {
        size_t o = base + j0 + j;
        float c00 = cc[3 * o], c01 = cc[3 * o + 1], c11 = cc[3 * o + 2];
        float dinv = NHL2E / (c00 * c11 - c01 * c01);
        float2 p = cp2[o];
        sA[j] = make_float4(p.x, p.y, c11 * dinv, -2.0f * c01 * dinv);
        sB[j] = make_float4(c00 * dinv, cw[o], 0.f, 0.f);
    }
    __syncthreads();

    int i0 = tile * 512 + threadIdx.x;
    int i1 = i0 + 256;
    bool v0 = i0 < N, v1 = i1 < N;
    float pa0 = 0.f, pa1 = 0.f, pb0 = 0.f, pb1 = 0.f;
    if (v0) { float2 p = cp2[base + i0]; pa0 = p.x; pa1 = p.y; }
    if (v1) { float2 p = cp2[base + i1]; pb0 = p.x; pb1 = p.y; }

    float s0 = 0.f, s1 = 0.f;
    for (int j = 0; j < cnt; ++j) {
        float4 a = sA[j];
        float4 b = sB[j];
        float d0 = pa0 - a.x, d1 = pa1 - a.y;
        float t  = fmaf(d1, a.w, d0 * a.z);
        float g  = fmaf(d0, t, d1 * (d1 * b.x));
        s0 = fmaf(b.y, __builtin_amdgcn_exp2f(g), s0);
        float e0 = pb0 - a.x, e1 = pb1 - a.y;
        float u  = fmaf(e1, a.w, e0 * a.z);
        float h  = fmaf(e0, u, e1 * (e1 * b.x));
        s1 = fmaf(b.y, __builtin_amdgcn_exp2f(h), s1);
    }
    if (v0) part[(size_t)js * BLN + base + i0] = s0;
    if (v1) part[(size_t)js * BLN + base + i1] = s1;
}

// --- relu-fit finish + top-k (key64 wave-shuffle argmax) + gather -----------
__device__ __forceinline__ unsigned int shfl_down_u32(unsigned int v, int off) {
    return (unsigned int)__shfl_down((int)v, off, 64);
}
__global__ __launch_bounds__(256) void topk_kernel(
        const float* __restrict__ part, const float* __restrict__ cw,
        const float* __restrict__ cp, const float* __restrict__ cc,
        float* __restrict__ dw, float* __restrict__ dp, float* __restrict__ dc,
        int N, int K, int JS, int BLN) {
    __shared__ unsigned long long skey[1280];
    __shared__ float swn[1280];
    __shared__ unsigned long long wred[4];
    __shared__ int sel[32];
    int bl = blockIdx.x;          // b*L + l
    size_t base = (size_t)bl * N;
    int t = threadIdx.x;

    for (int j = t; j < N; j += 256) {
        float s = 0.f;
        for (int q = 0; q < JS; ++q) s += part[(size_t)q * BLN + base + j];
        float denom = (fabsf(s) > 1e-6f) ? s : 1e-6f;
        float wn = cw[base + j] * (fmaxf(s, 0.f) / denom);
        swn[j] = wn;
        float c00 = cc[3 * (base + j)], c01 = cc[3 * (base + j) + 1],
              c11 = cc[3 * (base + j) + 2];
        float det = c00 * c11 - c01 * c01;
        float sc = fabsf(wn) * sqrtf(fmaxf(det, 1e-12f));
        unsigned int ub = __float_as_uint(sc) | 0x80000000u;   // sc >= 0: monotone
        skey[j] = ((unsigned long long)ub << 32) | (unsigned int)(~j);
    }
    __syncthreads();

    int lane = t & 63, wid = t >> 6;
    for (int r = 0; r < K; ++r) {
        unsigned long long k = 0ull;
        for (int j = t; j < N; j += 256) { unsigned long long v = skey[j]; if (v > k) k = v; }
        unsigned int lo = (unsigned int)k, hi = (unsigned int)(k >> 32);
        for (int off = 32; off > 0; off >>= 1) {
            unsigned int olo = shfl_down_u32(lo, off);
            unsigned int ohi = shfl_down_u32(hi, off);
            if (ohi > hi || (ohi == hi && olo > lo)) { hi = ohi; lo = olo; }
        }
        if (lane == 0) wred[wid] = ((unsigned long long)hi << 32) | lo;
        __syncthreads();
        if (t == 0) {
            unsigned long long m = wred[0];
            for (int wq = 1; wq < 4; ++wq) if (wred[wq] > m) m = wred[wq];
            int idx = (int)(~(unsigned int)m);
            sel[r] = idx;
            skey[idx] = 0ull;
        }
        __syncthreads();
    }

    if (t < K) {
        int idx = sel[t];
        size_t j = base + idx;
        int o = bl * K + t;       // next-layer data layout, descending score order
        dw[o] = swn[idx];
        dp[2 * o] = cp[2 * j]; dp[2 * o + 1] = cp[2 * j + 1];
        dc[3 * o] = cc[3 * j]; dc[3 * o + 1] = cc[3 * j + 1]; dc[3 * o + 2] = cc[3 * j + 2];
    }
}

// ------- per-channel CovScaleNorm + WeightBatchNorm (batch_norm=True) -------
__global__ void norm_kernel(float* __restrict__ dw, float* __restrict__ dp,
                            float* __restrict__ dc, int L, int K) {
    int l = blockIdx.x;           // one block per channel
    int t = threadIdx.x;          // 256
    __shared__ float red[256];
    int M = B * K;

    float tsum = 0.f;
    for (int u = t; u < M; u += 256) {
        int b = u / K, r = u % K;
        int idx = (b * L + l) * K + r;
        tsum += 0.5f * (dc[3 * idx] + dc[3 * idx + 2]);
    }
    red[t] = tsum; __syncthreads();
    for (int s = 128; s > 0; s >>= 1) { if (t < s) red[t] += red[t + s]; __syncthreads(); }
    float f = rsqrtf(red[0] / M + 1e-8f);
    __syncthreads();

    float f2 = f * f;
    float asum = 0.f;
    for (int u = t; u < M; u += 256) {
        int b = u / K, r = u % K;
        int idx = (b * L + l) * K + r;
        float c00 = dc[3 * idx] * f2, c01 = dc[3 * idx + 1] * f2, c11 = dc[3 * idx + 2] * f2;
        dc[3 * idx] = c00; dc[3 * idx + 1] = c01; dc[3 * idx + 2] = c11;
        dp[2 * idx] *= f; dp[2 * idx + 1] *= f;
        float det = c00 * c11 - c01 * c01;
        asum += fabsf(dw[idx] * TWO_PI_F * sqrtf(fmaxf(det, 1e-12f)));
    }
    red[t] = asum; __syncthreads();
    for (int s = 128; s > 0; s >>= 1) { if (t < s) red[t] += red[t + s]; __syncthreads(); }
    float scale = red[0] / M + 1e-6f;
    __syncthreads();

    for (int u = t; u < M; u += 256) {
        int b = u / K, r = u % K;
        dw[(b * L + l) * K + r] /= scale;
    }
}

// ---- layer-2: relu-finish + norm + integrate fused (w-norm linear in w) ----
__global__ void final_layer_kernel(const float* __restrict__ part,
                                   const float* __restrict__ cw,
                                   const float* __restrict__ cc,
                                   float* __restrict__ xbuf,
                                   int L, int N, int JS, int BLN) {
    int co = blockIdx.x;          // 10 blocks
    int t  = threadIdx.x;         // 256
    __shared__ float red[256];
    int M = B * N;

    float tsum = 0.f;
    for (int b = 0; b < B; ++b) {
        size_t base = (size_t)(b * L + co) * N;
        for (int n = t; n < N; n += 256)
            tsum += 0.5f * (cc[3 * (base + n)] + cc[3 * (base + n) + 2]);
    }
    red[t] = tsum; __syncthreads();
    for (int s = 128; s > 0; s >>= 1) { if (t < s) red[t] += red[t + s]; __syncthreads(); }
    float f = rsqrtf(red[0] / M + 1e-8f);
    __syncthreads();

    float f4 = f * f * f * f;
    float asum = 0.f;
    float bsums[B];
#pragma unroll
    for (int b = 0; b < B; ++b) {
        size_t base = (size_t)(b * L + co) * N;
        float ssum = 0.f;
        for (int n = t; n < N; n += 256) {
            float s = 0.f;
            for (int q = 0; q < JS; ++q) s += part[(size_t)q * BLN + base + n];
            float denom = (fabsf(s) > 1e-6f) ? s : 1e-6f;
            float wn = cw[base + n] * (fmaxf(s, 0.f) / denom);
            float c00 = cc[3 * (base + n)], c01 = cc[3 * (base + n) + 1],
                  c11 = cc[3 * (base + n) + 2];
            float det = (c00 * c11 - c01 * c01) * f4;
            float integ = wn * TWO_PI_F * sqrtf(fmaxf(det, 1e-12f));
            asum += fabsf(integ);
            ssum += integ;
        }
        bsums[b] = ssum;
    }
    red[t] = asum; __syncthreads();
    for (int s = 128; s > 0; s >>= 1) { if (t < s) red[t] += red[t + s]; __syncthreads(); }
    float scale = red[0] / M + 1e-6f;
    __syncthreads();

    for (int b = 0; b < B; ++b) {
        red[t] = bsums[b]; __syncthreads();
        for (int s = 128; s > 0; s >>= 1) { if (t < s) red[t] += red[t + s]; __syncthreads(); }
        if (t == 0) xbuf[b * L + co] = red[0] / scale;
        __syncthreads();
    }
}

// ---------------- final BatchNorm1d (training) + log_softmax ----------------
__global__ void final_bn_kernel(const float* __restrict__ xbuf, float* __restrict__ out) {
    __shared__ float xs[80];
    __shared__ float xn[80];
    int t = threadIdx.x;
    if (t < 80) xs[t] = xbuf[t];
    __syncthreads();
    if (t < 10) {
        float mu = 0.f;
        for (int b = 0; b < 8; ++b) mu += xs[b * 10 + t];
        mu *= 0.125f;
        float var = 0.f;
        for (int b = 0; b < 8; ++b) { float d = xs[b * 10 + t] - mu; var += d * d; }
        var *= 0.125f;
        float inv = rsqrtf(var + 1e-5f);
        for (int b = 0; b < 8; ++b) xn[b * 10 + t] = (xs[b * 10 + t] - mu) * inv;
    }
    __syncthreads();
    if (t < 8) {
        float mx = -INFINITY;
        for (int c = 0; c < 10; ++c) mx = fmaxf(mx, xn[t * 10 + c]);
        float se = 0.f;
        for (int c = 0; c < 10; ++c) se += expf(xn[t * 10 + c] - mx);
        float lse = mx + logf(se);
        for (int c = 0; c < 10; ++c) out[t * 10 + c] = xn[t * 10 + c] - lse;
    }
}

extern "C" void kernel_launch(void* const* d_in, const int* in_sizes, int n_in,
                              void* d_out, int out_size, void* d_ws, size_t ws_size,
                              hipStream_t stream) {
    const float* in_w = (const float*)d_in[0];
    const float* in_p = (const float*)d_in[1];
    const float* in_c = (const float*)d_in[2];
    const float* kw[3] = {(const float*)d_in[3], (const float*)d_in[6], (const float*)d_in[9]};
    const float* kp[3] = {(const float*)d_in[4], (const float*)d_in[7], (const float*)d_in[10]};
    const float* kc[3] = {(const float*)d_in[5], (const float*)d_in[8], (const float*)d_in[11]};

    float* ws   = (float*)d_ws;
    float* dw   = ws + OFF_DW;
    float* dp   = ws + OFF_DP;
    float* dc   = ws + OFF_DC;
    float* cw   = ws + OFF_CW;
    float* cp   = ws + OFF_CP;
    float* cc   = ws + OFF_CC;
    float* partb = ws + OFF_PART;
    float* out  = (float*)d_out;

    // pick j-split from available workspace (constant across calls)
    size_t avail_f = ws_size / 4;
    int JS = 1;
    if (avail_f >= OFF_PART + 4 * BLN_MAX + 80) JS = 4;
    else if (avail_f >= OFF_PART + 2 * BLN_MAX + 80) JS = 2;
    float* xb = partb + (size_t)JS * BLN_MAX;

    norm0_kernel<<<B, 128, 0, stream>>>(in_w, in_p, in_c, dw, dp, dc);

    const int Cos[3] = {8, 16, 10};
    const int Cis[3] = {1, 8, 16};
    const int Nds[3] = {128, 32, 16};
    const int Ks[3]  = {32, 16, -1};

    for (int layer = 0; layer < 3; ++layer) {
        int Co = Cos[layer], Ci = Cis[layer], Nd = Nds[layer];
        int N = Ci * Nd * NK;
        int blc = B * Co;
        int total = blc * N;
        int tiles = (N + 511) / 512;
        int chunk = (N + JS - 1) / JS;
        int BLN = blc * N;

        conv_kernel<<<(total + 255) / 256, 256, 0, stream>>>(
            dw, dp, dc, kw[layer], kp[layer], kc[layer], cw, cp, cc, Co, Ci, Nd, total);
        eval_kernel<<<blc * tiles * JS, 256, (size_t)chunk * 32, stream>>>(
            cw, cp, cc, partb, N, tiles, JS, chunk, BLN);
        if (layer < 2) {
            topk_kernel<<<blc, 256, 0, stream>>>(partb, cw, cp, cc, dw, dp, dc,
                                                 N, Ks[layer], JS, BLN);
            norm_kernel<<<Co, 256, 0, stream>>>(dw, dp, dc, Co, Ks[layer]);
        } else {
            final_layer_kernel<<<Co, 256, 0, stream>>>(partb, cw, cc, xb, Co, N, JS, BLN);
        }
    }
    final_bn_kernel<<<1, 128, 0, stream>>>(xb, out);
}

// Round 3
// 277.766 us; speedup vs baseline: 1.5643x; 1.2150x over previous
//
#include <hip/hip_runtime.h>
#include <math.h>

#define TWO_PI_F 6.283185307179586f

// Problem dims (fixed by setup_inputs)
constexpr int B   = 8;
constexpr int NIN = 128;
constexpr int NK  = 5;

// Workspace layout (in floats)
constexpr size_t OFF_DW  = 0;         // 2048
constexpr size_t OFF_DP  = 2048;      // 4096  (2 per comp)
constexpr size_t OFF_DC  = 6144;      // 6144  (3 per comp, symmetric 2x2)
constexpr size_t OFF_CW  = 12288;     // 163840
constexpr size_t OFF_CP  = 176128;    // 327680
constexpr size_t OFF_CC  = 503808;    // 491520
constexpr size_t OFF_PART = 995328;   // JS * 163840 partial sums (JS from ws_size)
constexpr size_t BLN_MAX  = 163840;   // max bl_count * N over layers

// ---------------- norm0: per-sample CovScaleNorm + WeightBatchNorm ----------
__global__ void norm0_kernel(const float* __restrict__ in_w,
                             const float* __restrict__ in_p,
                             const float* __restrict__ in_c,
                             float* __restrict__ dw, float* __restrict__ dp,
                             float* __restrict__ dc) {
    int b = blockIdx.x;           // 8 blocks
    int t = threadIdx.x;          // 128 threads, one comp each
    __shared__ float red[128];
    int idx = b * NIN + t;
    float w  = in_w[idx];
    float p0 = in_p[2 * idx], p1 = in_p[2 * idx + 1];
    float c00 = in_c[4 * idx], c01 = in_c[4 * idx + 1], c11 = in_c[4 * idx + 3];

    red[t] = 0.5f * (c00 + c11);               // trace/D
    __syncthreads();
    for (int s = 64; s > 0; s >>= 1) { if (t < s) red[t] += red[t + s]; __syncthreads(); }
    float f = rsqrtf(red[0] / NIN + 1e-8f);
    __syncthreads();

    float f2 = f * f;
    p0 *= f; p1 *= f; c00 *= f2; c01 *= f2; c11 *= f2;
    float det = c00 * c11 - c01 * c01;
    float integ = w * TWO_PI_F * sqrtf(fmaxf(det, 1e-12f));
    red[t] = fabsf(integ);
    __syncthreads();
    for (int s = 64; s > 0; s >>= 1) { if (t < s) red[t] += red[t + s]; __syncthreads(); }
    float scale = red[0] / NIN + 1e-6f;

    w /= scale;
    dw[idx] = w;
    dp[2 * idx] = p0; dp[2 * idx + 1] = p1;
    dc[3 * idx] = c00; dc[3 * idx + 1] = c01; dc[3 * idx + 2] = c11;
}

// ---------------- gm_convolve: one thread per output component --------------
__global__ void conv_kernel(const float* __restrict__ dw, const float* __restrict__ dp,
                            const float* __restrict__ dc,
                            const float* __restrict__ kw, const float* __restrict__ kp,
                            const float* __restrict__ kc,
                            float* __restrict__ cw, float* __restrict__ cp,
                            float* __restrict__ cc,
                            int Co, int Ci, int Nd, int total) {
    int t = blockIdx.x * blockDim.x + threadIdx.x;
    if (t >= total) return;
    int N  = Ci * Nd * NK;
    int n  = t % N;
    int bc = t / N;
    int co = bc % Co;
    int b  = bc / Co;
    int ci  = n / (Nd * NK);
    int rem = n % (Nd * NK);
    int nd  = rem / NK;
    int nk  = rem % NK;
    int di = (b * Ci + ci) * Nd + nd;
    int ki = (co * Ci + ci) * NK + nk;

    float wd = dw[di], pd0 = dp[2 * di], pd1 = dp[2 * di + 1];
    float d00 = dc[3 * di], d01 = dc[3 * di + 1], d11 = dc[3 * di + 2];
    float wk = kw[ki], pk0 = kp[2 * ki], pk1 = kp[2 * ki + 1];
    float k00 = kc[4 * ki], k01 = kc[4 * ki + 1], k11 = kc[4 * ki + 3];

    float s00 = d00 + k00, s01 = d01 + k01, s11 = d11 + k11;
    float det_d = d00 * d11 - d01 * d01;
    float det_k = k00 * k11 - k01 * k01;
    float det_s = s00 * s11 - s01 * s01;
    float amp = TWO_PI_F * sqrtf(fmaxf(det_d * det_k / fmaxf(det_s, 1e-12f), 1e-20f));

    cw[t] = wd * wk * amp;
    cp[2 * t] = pd0 + pk0; cp[2 * t + 1] = pd1 + pk1;
    cc[3 * t] = s00; cc[3 * t + 1] = s01; cc[3 * t + 2] = s11;
}

// ------------- gm_eval_at_centers: partial sums over a j-chunk --------------
// grid = bl_count * tiles * JS; block 256 threads, each owning 2 i's.
// LDS: packed float4 {p0,p1,A00,A01h} and {A11,w,-,-} with A = -0.5*log2e*inv(C).
__global__ __launch_bounds__(256) void eval_kernel(
        const float* __restrict__ cw, const float* __restrict__ cp,
        const float* __restrict__ cc, float* __restrict__ part,
        int N, int tiles, int JS, int chunk, int BLN) {
    extern __shared__ float4 sm[];
    float4* sA = sm;
    float4* sB = sm + chunk;
    int blk = blockIdx.x;
    int js   = blk % JS;
    int tile = (blk / JS) % tiles;
    int bl   = blk / (JS * tiles);
    int j0 = js * chunk;
    int cnt = min(chunk, N - j0);
    size_t base = (size_t)bl * N;
    const float NHL2E = -0.72134752044448f;   // -0.5 * log2(e)
    const float2* cp2 = (const float2*)cp;

    for (int j = threadIdx.x; j < cnt; j += 256) {
        size_t o = base + j0 + j;
        float c00 = cc[3 * o], c01 = cc[3 * o + 1], c11 = cc[3 * o + 2];
        float dinv = NHL2E / (c00 * c11 - c01 * c01);
        float2 p = cp2[o];
        sA[j] = make_float4(p.x, p.y, c11 * dinv, -2.0f * c01 * dinv);
        sB[j] = make_float4(c00 * dinv, cw[o], 0.f, 0.f);
    }
    __syncthreads();

    int i0 = tile * 512 + threadIdx.x;
    int i1 = i0 + 256;
    bool v0 = i0 < N, v1 = i1 < N;
    float pa0 = 0.f, pa1 = 0.f, pb0 = 0.f, pb1 = 0.f;
    if (v0) { float2 p = cp2[base + i0]; pa0 = p.x; pa1 = p.y; }
    if (v1) { float2 p = cp2[base + i1]; pb0 = p.x; pb1 = p.y; }

    float s0 = 0.f, s1 = 0.f;
    for (int j = 0; j < cnt; ++j) {
        float4 a = sA[j];
        float4 b = sB[j];
        float d0 = pa0 - a.x, d1 = pa1 - a.y;
        float t  = fmaf(d1, a.w, d0 * a.z);
        float g  = fmaf(d0, t, d1 * (d1 * b.x));
        s0 = fmaf(b.y, __builtin_amdgcn_exp2f(g), s0);
        float e0 = pb0 - a.x, e1 = pb1 - a.y;
        float u  = fmaf(e1, a.w, e0 * a.z);
        float h  = fmaf(e0, u, e1 * (e1 * b.x));
        s1 = fmaf(b.y, __builtin_amdgcn_exp2f(h), s1);
    }
    if (v0) part[(size_t)js * BLN + base + i0] = s0;
    if (v1) part[(size_t)js * BLN + base + i1] = s1;
}

// --- relu-fit finish + top-k (key64 wave-shuffle argmax) + gather -----------
__device__ __forceinline__ unsigned int shfl_down_u32(unsigned int v, int off) {
    return (unsigned int)__shfl_down((int)v, off, 64);
}
__global__ __launch_bounds__(256) void topk_kernel(
        const float* __restrict__ part, const float* __restrict__ cw,
        const float* __restrict__ cp, const float* __restrict__ cc,
        float* __restrict__ dw, float* __restrict__ dp, float* __restrict__ dc,
        int N, int K, int JS, int BLN) {
    __shared__ unsigned long long skey[1280];
    __shared__ float swn[1280];
    __shared__ unsigned long long wred[4];
    __shared__ int sel[32];
    int bl = blockIdx.x;          // b*L + l
    size_t base = (size_t)bl * N;
    int t = threadIdx.x;

    for (int j = t; j < N; j += 256) {
        float s = 0.f;
        for (int q = 0; q < JS; ++q) s += part[(size_t)q * BLN + base + j];
        float denom = (fabsf(s) > 1e-6f) ? s : 1e-6f;
        float wn = cw[base + j] * (fmaxf(s, 0.f) / denom);
        swn[j] = wn;
        float c00 = cc[3 * (base + j)], c01 = cc[3 * (base + j) + 1],
              c11 = cc[3 * (base + j) + 2];
        float det = c00 * c11 - c01 * c01;
        float sc = fabsf(wn) * sqrtf(fmaxf(det, 1e-12f));
        unsigned int ub = __float_as_uint(sc) | 0x80000000u;   // sc >= 0: monotone
        skey[j] = ((unsigned long long)ub << 32) | (unsigned int)(~j);
    }
    __syncthreads();

    int lane = t & 63, wid = t >> 6;
    for (int r = 0; r < K; ++r) {
        unsigned long long k = 0ull;
        for (int j = t; j < N; j += 256) { unsigned long long v = skey[j]; if (v > k) k = v; }
        unsigned int lo = (unsigned int)k, hi = (unsigned int)(k >> 32);
        for (int off = 32; off > 0; off >>= 1) {
            unsigned int olo = shfl_down_u32(lo, off);
            unsigned int ohi = shfl_down_u32(hi, off);
            if (ohi > hi || (ohi == hi && olo > lo)) { hi = ohi; lo = olo; }
        }
        if (lane == 0) wred[wid] = ((unsigned long long)hi << 32) | lo;
        __syncthreads();
        if (t == 0) {
            unsigned long long m = wred[0];
            for (int wq = 1; wq < 4; ++wq) if (wred[wq] > m) m = wred[wq];
            int idx = (int)(~(unsigned int)m);
            sel[r] = idx;
            skey[idx] = 0ull;
        }
        __syncthreads();
    }

    if (t < K) {
        int idx = sel[t];
        size_t j = base + idx;
        int o = bl * K + t;       // next-layer data layout, descending score order
        dw[o] = swn[idx];
        dp[2 * o] = cp[2 * j]; dp[2 * o + 1] = cp[2 * j + 1];
        dc[3 * o] = cc[3 * j]; dc[3 * o + 1] = cc[3 * j + 1]; dc[3 * o + 2] = cc[3 * j + 2];
    }
}

// ------- per-channel CovScaleNorm + WeightBatchNorm (batch_norm=True) -------
__global__ void norm_kernel(float* __restrict__ dw, float* __restrict__ dp,
                            float* __restrict__ dc, int L, int K) {
    int l = blockIdx.x;           // one block per channel
    int t = threadIdx.x;          // 256
    __shared__ float red[256];
    int M = B * K;

    float tsum = 0.f;
    for (int u = t; u < M; u += 256) {
        int b = u / K, r = u % K;
        int idx = (b * L + l) * K + r;
        tsum += 0.5f * (dc[3 * idx] + dc[3 * idx + 2]);
    }
    red[t] = tsum; __syncthreads();
    for (int s = 128; s > 0; s >>= 1) { if (t < s) red[t] += red[t + s]; __syncthreads(); }
    float f = rsqrtf(red[0] / M + 1e-8f);
    __syncthreads();

    float f2 = f * f;
    float asum = 0.f;
    for (int u = t; u < M; u += 256) {
        int b = u / K, r = u % K;
        int idx = (b * L + l) * K + r;
        float c00 = dc[3 * idx] * f2, c01 = dc[3 * idx + 1] * f2, c11 = dc[3 * idx + 2] * f2;
        dc[3 * idx] = c00; dc[3 * idx + 1] = c01; dc[3 * idx + 2] = c11;
        dp[2 * idx] *= f; dp[2 * idx + 1] *= f;
        float det = c00 * c11 - c01 * c01;
        asum += fabsf(dw[idx] * TWO_PI_F * sqrtf(fmaxf(det, 1e-12f)));
    }
    red[t] = asum; __syncthreads();
    for (int s = 128; s > 0; s >>= 1) { if (t < s) red[t] += red[t + s]; __syncthreads(); }
    float scale = red[0] / M + 1e-6f;
    __syncthreads();

    for (int u = t; u < M; u += 256) {
        int b = u / K, r = u % K;
        dw[(b * L + l) * K + r] /= scale;
    }
}

// ---- layer-2 stage A: per-(b,co) partials; f factored out algebraically ----
// integ(f) = f^2 * wn*2pi*sqrt(det), so sums over n can be computed before f.
__global__ __launch_bounds__(256) void final_partial_kernel(
        const float* __restrict__ part, const float* __restrict__ cw,
        const float* __restrict__ cc,
        float* __restrict__ tbuf, float* __restrict__ ubuf, float* __restrict__ abuf,
        int N, int JS, int BLN) {
    int bl = blockIdx.x;          // b*Co + co  (80 blocks)
    size_t base = (size_t)bl * N;
    int t = threadIdx.x;
    __shared__ float r1[256], r2[256], r3[256];

    float tsum = 0.f, usum = 0.f, asum = 0.f;
    for (int n = t; n < N; n += 256) {
        size_t o = base + n;
        float c00 = cc[3 * o], c01 = cc[3 * o + 1], c11 = cc[3 * o + 2];
        tsum += 0.5f * (c00 + c11);
        float s = 0.f;
        for (int q = 0; q < JS; ++q) s += part[(size_t)q * BLN + o];
        float denom = (fabsf(s) > 1e-6f) ? s : 1e-6f;
        float wn = cw[o] * (fmaxf(s, 0.f) / denom);
        float det = fmaxf(c00 * c11 - c01 * c01, 1e-30f);
        float integ = wn * TWO_PI_F * sqrtf(det);
        usum += integ;
        asum += fabsf(integ);
    }
    r1[t] = tsum; r2[t] = usum; r3[t] = asum;
    __syncthreads();
    for (int s = 128; s > 0; s >>= 1) {
        if (t < s) { r1[t] += r1[t + s]; r2[t] += r2[t + s]; r3[t] += r3[t + s]; }
        __syncthreads();
    }
    if (t == 0) { tbuf[bl] = r1[0]; ubuf[bl] = r2[0]; abuf[bl] = r3[0]; }
}

// -------- finish: f per channel, scale, x; then BatchNorm1d + log_softmax ---
__global__ void final_bn_kernel(const float* __restrict__ tbuf,
                                const float* __restrict__ ubuf,
                                const float* __restrict__ abuf,
                                float* __restrict__ out, int L, int N) {
    __shared__ float xs[80];
    __shared__ float xn[80];
    int t = threadIdx.x;
    if (t < L) {
        int co = t;
        float tr = 0.f, a = 0.f;
        for (int b = 0; b < B; ++b) { tr += tbuf[b * L + co]; a += abuf[b * L + co]; }
        float m = tr / (float)(B * N);
        float f = rsqrtf(m + 1e-8f);
        float f2 = f * f;
        float scale = f2 * a / (float)(B * N) + 1e-6f;
        for (int b = 0; b < B; ++b) xs[b * L + co] = f2 * ubuf[b * L + co] / scale;
    }
    __syncthreads();
    if (t < L) {
        float mu = 0.f;
        for (int b = 0; b < B; ++b) mu += xs[b * L + t];
        mu *= 0.125f;
        float var = 0.f;
        for (int b = 0; b < B; ++b) { float d = xs[b * L + t] - mu; var += d * d; }
        var *= 0.125f;
        float inv = rsqrtf(var + 1e-5f);
        for (int b = 0; b < B; ++b) xn[b * L + t] = (xs[b * L + t] - mu) * inv;
    }
    __syncthreads();
    if (t < B) {
        float mx = -INFINITY;
        for (int c = 0; c < L; ++c) mx = fmaxf(mx, xn[t * L + c]);
        float se = 0.f;
        for (int c = 0; c < L; ++c) se += expf(xn[t * L + c] - mx);
        float lse = mx + logf(se);
        for (int c = 0; c < L; ++c) out[t * L + c] = xn[t * L + c] - lse;
    }
}

extern "C" void kernel_launch(void* const* d_in, const int* in_sizes, int n_in,
                              void* d_out, int out_size, void* d_ws, size_t ws_size,
                              hipStream_t stream) {
    const float* in_w = (const float*)d_in[0];
    const float* in_p = (const float*)d_in[1];
    const float* in_c = (const float*)d_in[2];
    const float* kw[3] = {(const float*)d_in[3], (const float*)d_in[6], (const float*)d_in[9]};
    const float* kp[3] = {(const float*)d_in[4], (const float*)d_in[7], (const float*)d_in[10]};
    const float* kc[3] = {(const float*)d_in[5], (const float*)d_in[8], (const float*)d_in[11]};

    float* ws   = (float*)d_ws;
    float* dw   = ws + OFF_DW;
    float* dp   = ws + OFF_DP;
    float* dc   = ws + OFF_DC;
    float* cw   = ws + OFF_CW;
    float* cp   = ws + OFF_CP;
    float* cc   = ws + OFF_CC;
    float* partb = ws + OFF_PART;
    float* out  = (float*)d_out;

    // pick j-split from available workspace (constant across calls)
    size_t avail_f = ws_size / 4;
    int JS = 1;
    if (avail_f >= OFF_PART + 4 * BLN_MAX + 256) JS = 4;
    else if (avail_f >= OFF_PART + 2 * BLN_MAX + 256) JS = 2;
    float* tbuf = partb + (size_t)JS * BLN_MAX;   // 80
    float* ubuf = tbuf + 80;                      // 80
    float* abuf = ubuf + 80;                      // 80

    norm0_kernel<<<B, 128, 0, stream>>>(in_w, in_p, in_c, dw, dp, dc);

    const int Cos[3] = {8, 16, 10};
    const int Cis[3] = {1, 8, 16};
    const int Nds[3] = {128, 32, 16};
    const int Ks[3]  = {32, 16, -1};

    for (int layer = 0; layer < 3; ++layer) {
        int Co = Cos[layer], Ci = Cis[layer], Nd = Nds[layer];
        int N = Ci * Nd * NK;
        int blc = B * Co;
        int total = blc * N;
        int tiles = (N + 511) / 512;
        int chunk = (N + JS - 1) / JS;
        int BLN = blc * N;

        conv_kernel<<<(total + 255) / 256, 256, 0, stream>>>(
            dw, dp, dc, kw[layer], kp[layer], kc[layer], cw, cp, cc, Co, Ci, Nd, total);
        eval_kernel<<<blc * tiles * JS, 256, (size_t)chunk * 32, stream>>>(
            cw, cp, cc, partb, N, tiles, JS, chunk, BLN);
        if (layer < 2) {
            topk_kernel<<<blc, 256, 0, stream>>>(partb, cw, cp, cc, dw, dp, dc,
                                                 N, Ks[layer], JS, BLN);
            norm_kernel<<<Co, 256, 0, stream>>>(dw, dp, dc, Co, Ks[layer]);
        } else {
            final_partial_kernel<<<blc, 256, 0, stream>>>(partb, cw, cc,
                                                          tbuf, ubuf, abuf, N, JS, BLN);
        }
    }
    final_bn_kernel<<<1, 128, 0, stream>>>(tbuf, ubuf, abuf, out, 10, 1280);
}

// Round 4
// 267.804 us; speedup vs baseline: 1.6225x; 1.0372x over previous
//
#include <hip/hip_runtime.h>
#include <math.h>

#define TWO_PI_F 6.283185307179586f

constexpr int B   = 8;
constexpr int NK  = 5;

// Workspace layout (in floats)
constexpr size_t OFF_DW  = 0;         // 2048
constexpr size_t OFF_DP  = 2048;      // 4096
constexpr size_t OFF_DC  = 6144;      // 6144
constexpr size_t OFF_CW  = 12288;     // 163840
constexpr size_t OFF_CP  = 176128;    // 327680
constexpr size_t OFF_CC  = 503808;    // 491520
constexpr size_t OFF_PART = 995328;   // JS * 163840 partial sums
constexpr size_t BLN_MAX  = 163840;

// =============== conv0: norm0 (per-sample) fused + gm_convolve ==============
// Layer 0: Ci=1, Co=8, Nd=128. 5120 outputs per b, 20 blocks of 256 per b.
__global__ __launch_bounds__(256) void conv0_kernel(
        const float* __restrict__ in_w, const float* __restrict__ in_p,
        const float* __restrict__ in_c,
        const float* __restrict__ kw, const float* __restrict__ kp,
        const float* __restrict__ kc,
        float* __restrict__ cw, float* __restrict__ cp, float* __restrict__ cc,
        int* __restrict__ cnt) {
    if (blockIdx.x == 0 && threadIdx.x == 0) *cnt = 0;   // final-kernel counter
    __shared__ float red[256];
    __shared__ float sw_[128], sp0_[128], sp1_[128];
    __shared__ float sc00_[128], sc01_[128], sc11_[128];
    int b = blockIdx.x / 20;
    int t = threadIdx.x;

    float w = 0.f, p0 = 0.f, p1 = 0.f, c00 = 0.f, c01 = 0.f, c11 = 0.f;
    if (t < 128) {
        int idx = b * 128 + t;
        w  = in_w[idx];
        p0 = in_p[2 * idx]; p1 = in_p[2 * idx + 1];
        c00 = in_c[4 * idx]; c01 = in_c[4 * idx + 1]; c11 = in_c[4 * idx + 3];
    }
    red[t] = (t < 128) ? 0.5f * (c00 + c11) : 0.f;
    __syncthreads();
    for (int s = 128; s > 0; s >>= 1) { if (t < s) red[t] += red[t + s]; __syncthreads(); }
    float f = rsqrtf(red[0] / 128.f + 1e-8f);
    __syncthreads();
    float f2 = f * f;
    p0 *= f; p1 *= f; c00 *= f2; c01 *= f2; c11 *= f2;
    float det = c00 * c11 - c01 * c01;
    float integ = w * TWO_PI_F * sqrtf(fmaxf(det, 1e-12f));
    red[t] = (t < 128) ? fabsf(integ) : 0.f;
    __syncthreads();
    for (int s = 128; s > 0; s >>= 1) { if (t < s) red[t] += red[t + s]; __syncthreads(); }
    float scale = red[0] / 128.f + 1e-6f;
    __syncthreads();
    if (t < 128) {
        sw_[t] = w / scale; sp0_[t] = p0; sp1_[t] = p1;
        sc00_[t] = c00; sc01_[t] = c01; sc11_[t] = c11;
    }
    __syncthreads();

    int r  = (blockIdx.x % 20) * 256 + t;   // [0,5120)
    int co = r / 640;
    int n  = r % 640;
    int nd = n / 5, nk = n % 5;
    int ki = co * 5 + nk;

    float wd = sw_[nd], pd0 = sp0_[nd], pd1 = sp1_[nd];
    float d00 = sc00_[nd], d01 = sc01_[nd], d11 = sc11_[nd];
    float wk = kw[ki], pk0 = kp[2 * ki], pk1 = kp[2 * ki + 1];
    float k00 = kc[4 * ki], k01 = kc[4 * ki + 1], k11 = kc[4 * ki + 3];

    float s00 = d00 + k00, s01 = d01 + k01, s11 = d11 + k11;
    float det_d = d00 * d11 - d01 * d01;
    float det_k = k00 * k11 - k01 * k01;
    float det_s = s00 * s11 - s01 * s01;
    float amp = TWO_PI_F * sqrtf(fmaxf(det_d * det_k / fmaxf(det_s, 1e-12f), 1e-20f));

    int o = b * 5120 + r;
    cw[o] = wd * wk * amp;
    cp[2 * o] = pd0 + pk0; cp[2 * o + 1] = pd1 + pk1;
    cc[3 * o] = s00; cc[3 * o + 1] = s01; cc[3 * o + 2] = s11;
}

// ========= convN: deferred per-channel norm (from topk partials) + conv =====
__global__ __launch_bounds__(256) void convN_kernel(
        const float* __restrict__ dw, const float* __restrict__ dp,
        const float* __restrict__ dc,
        const float* __restrict__ kw, const float* __restrict__ kp,
        const float* __restrict__ kc,
        const float* __restrict__ trp, const float* __restrict__ aip,
        float* __restrict__ cw, float* __restrict__ cp, float* __restrict__ cc,
        int Co, int Ci, int Nd, int total) {
    int t = blockIdx.x * blockDim.x + threadIdx.x;
    if (t >= total) return;
    int N  = Ci * Nd * NK;
    int n  = t % N;
    int bc = t / N;
    int co = bc % Co;
    int b  = bc / Co;
    int ci  = n / (Nd * NK);
    int rem = n % (Nd * NK);
    int nd  = rem / NK;
    int nk  = rem % NK;
    int di = (b * Ci + ci) * Nd + nd;
    int ki = (co * Ci + ci) * NK + nk;

    // deferred norm factors for input channel ci
    float str = 0.f, sai = 0.f;
    for (int bb = 0; bb < B; ++bb) { str += trp[ci * B + bb]; sai += aip[ci * B + bb]; }
    float M = (float)(B * Nd);
    float f = rsqrtf(str / M + 1e-8f);
    float f2 = f * f;
    float scale = f2 * sai / M + 1e-6f;

    float wd = dw[di] / scale;
    float pd0 = f * dp[2 * di], pd1 = f * dp[2 * di + 1];
    float d00 = f2 * dc[3 * di], d01 = f2 * dc[3 * di + 1], d11 = f2 * dc[3 * di + 2];
    float wk = kw[ki], pk0 = kp[2 * ki], pk1 = kp[2 * ki + 1];
    float k00 = kc[4 * ki], k01 = kc[4 * ki + 1], k11 = kc[4 * ki + 3];

    float s00 = d00 + k00, s01 = d01 + k01, s11 = d11 + k11;
    float det_d = d00 * d11 - d01 * d01;
    float det_k = k00 * k11 - k01 * k01;
    float det_s = s00 * s11 - s01 * s01;
    float amp = TWO_PI_F * sqrtf(fmaxf(det_d * det_k / fmaxf(det_s, 1e-12f), 1e-20f));

    cw[t] = wd * wk * amp;
    cp[2 * t] = pd0 + pk0; cp[2 * t + 1] = pd1 + pk1;
    cc[3 * t] = s00; cc[3 * t + 1] = s01; cc[3 * t + 2] = s11;
}

// ================= eval: j-expanded 6-term fma form, IT i's/thread ==========
// g = x0*A00 + x1*A01h + x2*A11 + pi0*u0 + pi1*u1 + cj  (A = -0.5*log2e*inv C)
template <int BLOCK, int IT>
__global__ __launch_bounds__(BLOCK) void eval_kernel(
        const float* __restrict__ cw, const float* __restrict__ cp,
        const float* __restrict__ cc, float* __restrict__ part,
        int N, int JS, int chunk, int BLN) {
    extern __shared__ float4 sm[];
    float4* sA = sm;
    float4* sB = sm + chunk;
    int blk = blockIdx.x;
    int js = blk % JS;
    int bl = blk / JS;
    int j0 = js * chunk;
    int cnt = min(chunk, N - j0);
    size_t base = (size_t)bl * N;
    const float NHL2E = -0.72134752044448f;   // -0.5 * log2(e)
    const float2* cp2 = (const float2*)cp;

    for (int j = threadIdx.x; j < cnt; j += BLOCK) {
        size_t o = base + j0 + j;
        float c00 = cc[3 * o], c01 = cc[3 * o + 1], c11 = cc[3 * o + 2];
        float dinv = NHL2E / (c00 * c11 - c01 * c01);
        float A00 = c11 * dinv, A01h = -2.0f * c01 * dinv, A11 = c00 * dinv;
        float2 pj = cp2[o];
        float u0 = -(2.0f * A00 * pj.x + A01h * pj.y);
        float u1 = -(A01h * pj.x + 2.0f * A11 * pj.y);
        float cj = (A00 * pj.x + A01h * pj.y) * pj.x + A11 * pj.y * pj.y;
        sA[j] = make_float4(A00, A01h, A11, u0);
        sB[j] = make_float4(u1, cj, cw[o], 0.f);
    }
    __syncthreads();

    float pi0[IT], pi1[IT], x0[IT], x1[IT], x2[IT], acc[IT];
#pragma unroll
    for (int u = 0; u < IT; ++u) {
        float2 p = cp2[base + u * BLOCK + threadIdx.x];
        pi0[u] = p.x; pi1[u] = p.y;
        x0[u] = p.x * p.x; x1[u] = p.x * p.y; x2[u] = p.y * p.y;
        acc[u] = 0.f;
    }

    for (int j = 0; j < cnt; ++j) {
        float4 a = sA[j];
        float4 b = sB[j];
#pragma unroll
        for (int u = 0; u < IT; ++u) {
            float g = fmaf(x0[u], a.x, fmaf(x1[u], a.y, fmaf(x2[u], a.z,
                      fmaf(pi0[u], a.w, fmaf(pi1[u], b.x, b.y)))));
            acc[u] = fmaf(b.z, __builtin_amdgcn_exp2f(g), acc[u]);
        }
    }
#pragma unroll
    for (int u = 0; u < IT; ++u)
        part[(size_t)js * BLN + base + u * BLOCK + threadIdx.x] = acc[u];
}

// ===== topk: relu-finish + iterative argmax (cached local max) + gather =====
// Also emits per-(b,l) norm partials (trace-sum, |integral|-sum) for next conv.
__device__ __forceinline__ unsigned int shfl_down_u32(unsigned int v, int off) {
    return (unsigned int)__shfl_down((int)v, off, 64);
}
__global__ __launch_bounds__(256) void topk_kernel(
        const float* __restrict__ part, const float* __restrict__ cw,
        const float* __restrict__ cp, const float* __restrict__ cc,
        float* __restrict__ dw, float* __restrict__ dp, float* __restrict__ dc,
        float* __restrict__ trp, float* __restrict__ aip,
        int N, int K, int JS, int BLN, int L) {
    __shared__ unsigned long long skey[1280];
    __shared__ float swn[1280];
    __shared__ unsigned long long wred[4];
    __shared__ unsigned long long bk;
    __shared__ int sel[32];
    int blv = blockIdx.x;          // b*L + l
    int b = blv / L, l = blv % L;
    size_t base = (size_t)blv * N;
    int t = threadIdx.x;

    for (int j = t; j < N; j += 256) {
        float s = 0.f;
        for (int q = 0; q < JS; ++q) s += part[(size_t)q * BLN + base + j];
        float denom = (fabsf(s) > 1e-6f) ? s : 1e-6f;
        float wn = cw[base + j] * (fmaxf(s, 0.f) / denom);
        swn[j] = wn;
        float c00 = cc[3 * (base + j)], c01 = cc[3 * (base + j) + 1],
              c11 = cc[3 * (base + j) + 2];
        float det = c00 * c11 - c01 * c01;
        float sc = fabsf(wn) * sqrtf(fmaxf(det, 1e-12f));
        unsigned int ub = __float_as_uint(sc) | 0x80000000u;
        skey[j] = ((unsigned long long)ub << 32) | (unsigned int)(~j);
    }
    __syncthreads();

    unsigned long long mk = 0ull;
    for (int j = t; j < N; j += 256) { unsigned long long v = skey[j]; if (v > mk) mk = v; }

    int lane = t & 63, wid = t >> 6;
    for (int r = 0; r < K; ++r) {
        unsigned int lo = (unsigned int)mk, hi = (unsigned int)(mk >> 32);
        for (int off = 32; off > 0; off >>= 1) {
            unsigned int olo = shfl_down_u32(lo, off);
            unsigned int ohi = shfl_down_u32(hi, off);
            if (ohi > hi || (ohi == hi && olo > lo)) { hi = ohi; lo = olo; }
        }
        if (lane == 0) wred[wid] = ((unsigned long long)hi << 32) | lo;
        __syncthreads();
        if (t == 0) {
            unsigned long long m = wred[0];
            for (int wq = 1; wq < 4; ++wq) if (wred[wq] > m) m = wred[wq];
            sel[r] = (int)(~(unsigned int)m);
            bk = m;
        }
        __syncthreads();
        unsigned long long bkv = bk;
        if (mk == bkv && mk != 0ull) {          // unique owner rescans its slots
            int idx = (int)(~(unsigned int)bkv);
            skey[idx] = 0ull;
            mk = 0ull;
            for (int j = t; j < N; j += 256) { unsigned long long v = skey[j]; if (v > mk) mk = v; }
        }
    }

    float tr_c = 0.f, ai_c = 0.f;
    if (t < K) {
        int idx = sel[t];
        size_t j = base + idx;
        int o = blv * K + t;
        float wn = swn[idx];
        float c00 = cc[3 * j], c01 = cc[3 * j + 1], c11 = cc[3 * j + 2];
        dw[o] = wn;
        dp[2 * o] = cp[2 * j]; dp[2 * o + 1] = cp[2 * j + 1];
        dc[3 * o] = c00; dc[3 * o + 1] = c01; dc[3 * o + 2] = c11;
        tr_c = 0.5f * (c00 + c11);
        float det = c00 * c11 - c01 * c01;
        ai_c = fabsf(wn * TWO_PI_F * sqrtf(fmaxf(det, 1e-12f)));
    }
    if (t < 64) {
        for (int off = 32; off > 0; off >>= 1) {
            tr_c += __shfl_down(tr_c, off, 64);
            ai_c += __shfl_down(ai_c, off, 64);
        }
        if (t == 0) { trp[l * B + b] = tr_c; aip[l * B + b] = ai_c; }
    }
}

// ==== final: per-(b,co) partials; last block does norm + BN + log_softmax ===
__global__ __launch_bounds__(256) void final_kernel(
        const float* __restrict__ part, const float* __restrict__ cw,
        const float* __restrict__ cc,
        float* __restrict__ tbuf, float* __restrict__ ubuf, float* __restrict__ abuf,
        int* __restrict__ cnt, float* __restrict__ out,
        int L, int N, int JS, int BLN) {
    int blv = blockIdx.x;          // b*L + co (80 blocks)
    size_t base = (size_t)blv * N;
    int t = threadIdx.x;
    __shared__ float r1[256], r2[256], r3[256];

    float tsum = 0.f, usum = 0.f, asum = 0.f;
    for (int n = t; n < N; n += 256) {
        size_t o = base + n;
        float c00 = cc[3 * o], c01 = cc[3 * o + 1], c11 = cc[3 * o + 2];
        tsum += 0.5f * (c00 + c11);
        float s = 0.f;
        for (int q = 0; q < JS; ++q) s += part[(size_t)q * BLN + o];
        float denom = (fabsf(s) > 1e-6f) ? s : 1e-6f;
        float wn = cw[o] * (fmaxf(s, 0.f) / denom);
        float det = fmaxf(c00 * c11 - c01 * c01, 1e-30f);
        float integ = wn * TWO_PI_F * sqrtf(det);
        usum += integ;
        asum += fabsf(integ);
    }
    r1[t] = tsum; r2[t] = usum; r3[t] = asum;
    __syncthreads();
    for (int s = 128; s > 0; s >>= 1) {
        if (t < s) { r1[t] += r1[t + s]; r2[t] += r2[t + s]; r3[t] += r3[t + s]; }
        __syncthreads();
    }
    __shared__ int lastf;
    if (t == 0) {
        tbuf[blv] = r1[0]; ubuf[blv] = r2[0]; abuf[blv] = r3[0];
        __threadfence();
        lastf = (atomicAdd(cnt, 1) == (int)gridDim.x - 1);
    }
    __syncthreads();
    if (!lastf) return;
    __threadfence();

    __shared__ float xs[80];
    __shared__ float xn[80];
    if (t < L) {
        float tr = 0.f, a = 0.f;
        for (int bb = 0; bb < B; ++bb) { tr += tbuf[bb * L + t]; a += abuf[bb * L + t]; }
        float m = tr / (float)(B * N);
        float f = rsqrtf(m + 1e-8f);
        float f2 = f * f;
        float scale = f2 * a / (float)(B * N) + 1e-6f;
        for (int bb = 0; bb < B; ++bb) xs[bb * L + t] = f2 * ubuf[bb * L + t] / scale;
    }
    __syncthreads();
    if (t < L) {
        float mu = 0.f;
        for (int bb = 0; bb < B; ++bb) mu += xs[bb * L + t];
        mu *= 0.125f;
        float var = 0.f;
        for (int bb = 0; bb < B; ++bb) { float d = xs[bb * L + t] - mu; var += d * d; }
        var *= 0.125f;
        float inv = rsqrtf(var + 1e-5f);
        for (int bb = 0; bb < B; ++bb) xn[bb * L + t] = (xs[bb * L + t] - mu) * inv;
    }
    __syncthreads();
    if (t < B) {
        float mx = -INFINITY;
        for (int c = 0; c < L; ++c) mx = fmaxf(mx, xn[t * L + c]);
        float se = 0.f;
        for (int c = 0; c < L; ++c) se += expf(xn[t * L + c] - mx);
        float lse = mx + logf(se);
        for (int c = 0; c < L; ++c) out[t * L + c] = xn[t * L + c] - lse;
    }
}

extern "C" void kernel_launch(void* const* d_in, const int* in_sizes, int n_in,
                              void* d_out, int out_size, void* d_ws, size_t ws_size,
                              hipStream_t stream) {
    const float* in_w = (const float*)d_in[0];
    const float* in_p = (const float*)d_in[1];
    const float* in_c = (const float*)d_in[2];
    const float* kw[3] = {(const float*)d_in[3], (const float*)d_in[6], (const float*)d_in[9]};
    const float* kp[3] = {(const float*)d_in[4], (const float*)d_in[7], (const float*)d_in[10]};
    const float* kc[3] = {(const float*)d_in[5], (const float*)d_in[8], (const float*)d_in[11]};

    float* ws   = (float*)d_ws;
    float* dw   = ws + OFF_DW;
    float* dp   = ws + OFF_DP;
    float* dc   = ws + OFF_DC;
    float* cw   = ws + OFF_CW;
    float* cp   = ws + OFF_CP;
    float* cc   = ws + OFF_CC;
    float* partb = ws + OFF_PART;
    float* out  = (float*)d_out;

    size_t avail_f = ws_size / 4;
    int JS = 1;
    if (avail_f >= OFF_PART + 8 * BLN_MAX + 1024) JS = 8;
    else if (avail_f >= OFF_PART + 4 * BLN_MAX + 1024) JS = 4;
    else if (avail_f >= OFF_PART + 2 * BLN_MAX + 1024) JS = 2;

    float* tail = partb + (size_t)JS * BLN_MAX;
    float* trp0 = tail;          // 128
    float* aip0 = tail + 128;    // 128
    float* trp1 = tail + 256;    // 128
    float* aip1 = tail + 384;    // 128
    float* tbuf = tail + 512;    // 80
    float* ubuf = tail + 592;    // 80
    float* abuf = tail + 672;    // 80
    int*   cnt  = (int*)(tail + 752);

    // ---- layer 0: Ci=1, Co=8, Nd=128, N=640, K=32 ----
    {
        int N = 640, blc = B * 8;
        int chunk = (N + JS - 1) / JS, BLN = blc * N;
        conv0_kernel<<<160, 256, 0, stream>>>(in_w, in_p, in_c, kw[0], kp[0], kc[0],
                                              cw, cp, cc, cnt);
        eval_kernel<128, 5><<<blc * JS, 128, (size_t)chunk * 32, stream>>>(
            cw, cp, cc, partb, N, JS, chunk, BLN);
        topk_kernel<<<blc, 256, 0, stream>>>(partb, cw, cp, cc, dw, dp, dc,
                                             trp0, aip0, N, 32, JS, BLN, 8);
    }
    // ---- layer 1: Ci=8, Co=16, Nd=32, N=1280, K=16 ----
    {
        int Co = 16, Ci = 8, Nd = 32, N = 1280;
        int blc = B * Co, total = blc * N;
        int chunk = (N + JS - 1) / JS, BLN = blc * N;
        convN_kernel<<<(total + 255) / 256, 256, 0, stream>>>(
            dw, dp, dc, kw[1], kp[1], kc[1], trp0, aip0, cw, cp, cc, Co, Ci, Nd, total);
        eval_kernel<256, 5><<<blc * JS, 256, (size_t)chunk * 32, stream>>>(
            cw, cp, cc, partb, N, JS, chunk, BLN);
        topk_kernel<<<blc, 256, 0, stream>>>(partb, cw, cp, cc, dw, dp, dc,
                                             trp1, aip1, N, 16, JS, BLN, Co);
    }
    // ---- layer 2: Ci=16, Co=10, Nd=16, N=1280, keep all ----
    {
        int Co = 10, Ci = 16, Nd = 16, N = 1280;
        int blc = B * Co, total = blc * N;
        int chunk = (N + JS - 1) / JS, BLN = blc * N;
        convN_kernel<<<(total + 255) / 256, 256, 0, stream>>>(
            dw, dp, dc, kw[2], kp[2], kc[2], trp1, aip1, cw, cp, cc, Co, Ci, Nd, total);
        eval_kernel<256, 5><<<blc * JS, 256, (size_t)chunk * 32, stream>>>(
            cw, cp, cc, partb, N, JS, chunk, BLN);
        final_kernel<<<blc, 256, 0, stream>>>(partb, cw, cc, tbuf, ubuf, abuf,
                                              cnt, out, Co, N, JS, BLN);
    }
}

// Round 5
// 236.465 us; speedup vs baseline: 1.8375x; 1.1325x over previous
//
#include <hip/hip_runtime.h>
#include <math.h>

#define TWO_PI_F 6.283185307179586f

constexpr int B  = 8;
constexpr int JS = 8;

// Workspace layout (floats). JS=8 confirmed active in round 4 (WRITE_SIZE).
constexpr size_t OFF_DW   = 0;        // 2048
constexpr size_t OFF_DP   = 2048;     // 4096
constexpr size_t OFF_DC   = 6144;     // 6144
constexpr size_t OFF_CW   = 12288;    // 163840
constexpr size_t OFF_CP   = 176128;   // 327680
constexpr size_t OFF_CC   = 503808;   // 491520
constexpr size_t OFF_PART = 995328;   // 8 * 163840
constexpr size_t BLN_MAX  = 163840;

typedef short  s16x8 __attribute__((ext_vector_type(8)));
typedef float  f32x4 __attribute__((ext_vector_type(4)));

__device__ __forceinline__ short f2bf(float x) {          // RNE fp32->bf16 bits
    unsigned u = __float_as_uint(x);
    return (short)((u + 0x7fffu + ((u >> 16) & 1u)) >> 16);
}
__device__ __forceinline__ float bf2f(short s) {
    return __uint_as_float(((unsigned)(unsigned short)s) << 16);
}

// ---------- norm0 factors: per-sample f, scale (8 pairs) + cnt reset --------
__global__ void norm0f_kernel(const float* __restrict__ in_w,
                              const float* __restrict__ in_c,
                              float* __restrict__ fs0, float* __restrict__ sc0,
                              int* __restrict__ cnt) {
    if (blockIdx.x == 0 && threadIdx.x == 0) *cnt = 0;
    int b = blockIdx.x, t = threadIdx.x;   // 8 blocks x 128
    __shared__ float red[128];
    int idx = b * 128 + t;
    float w = in_w[idx];
    float c00 = in_c[4 * idx], c01 = in_c[4 * idx + 1], c11 = in_c[4 * idx + 3];
    red[t] = 0.5f * (c00 + c11);
    __syncthreads();
    for (int s = 64; s > 0; s >>= 1) { if (t < s) red[t] += red[t + s]; __syncthreads(); }
    float f = rsqrtf(red[0] / 128.f + 1e-8f);
    __syncthreads();
    float f2 = f * f;
    float det = (c00 * c11 - c01 * c01) * f2 * f2;
    red[t] = fabsf(w * TWO_PI_F * sqrtf(fmaxf(det, 1e-12f)));
    __syncthreads();
    for (int s = 64; s > 0; s >>= 1) { if (t < s) red[t] += red[t + s]; __syncthreads(); }
    if (t == 0) { fs0[b] = f; sc0[b] = red[0] / 128.f + 1e-6f; }
}

// ======== fused conv + MFMA eval: partial sums over one j-chunk =============
// g_ij = f_i . c_j (6 terms) via bf16 hi/lo split packed into K=18 of one
// 16x16x32 bf16 MFMA (X'=[fh,fh,fl], C'=[ch,cl,ch]).
template <int CO, int CI, int ND, bool L0>
__global__ __launch_bounds__(256) void eval_mfma_kernel(
        const float* __restrict__ dw, const float* __restrict__ dp,
        const float* __restrict__ dc,
        const float* __restrict__ kw, const float* __restrict__ kp,
        const float* __restrict__ kc,
        const float* __restrict__ trp, const float* __restrict__ aip,
        float* __restrict__ cw, float* __restrict__ cp, float* __restrict__ cc,
        float* __restrict__ part) {
    constexpr int N     = CI * ND * 5;
    constexpr int CHUNK = N / JS;                    // 80 or 160 (mult of 16)
    constexpr int JT    = CHUNK / 16;
    constexpr int ISUP  = (N % 256 == 0) ? 256 : 128;
    constexpr int NSUP  = N / ISUP;
    constexpr int NT    = ISUP / 64;                 // i-tiles per wave
    constexpr int ROWB  = 40;                        // shorts per row (80 B)
    constexpr int BLN   = B * CO * N;

    __shared__ __align__(16) short sX[ISUP * ROWB];
    __shared__ __align__(16) short sC[CHUNK * ROWB];
    __shared__ float sw_[CHUNK];
    __shared__ float sfac[CI], sscl[CI];

    int blk = blockIdx.x;
    int js = blk % JS;
    int bl = blk / JS;                 // b*CO + co
    int b = bl / CO, co = bl % CO;
    int t = threadIdx.x;
    size_t base = (size_t)bl * N;
    const float NHL2E = -0.72134752044448f;          // -0.5*log2(e)

    // deferred per-channel norm factors
    if (t < CI) {
        if (L0) { sfac[t] = trp[b]; sscl[t] = aip[b]; }     // fs0, sc0
        else {
            float str = 0.f, sai = 0.f;
            for (int bb = 0; bb < B; ++bb) { str += trp[t * B + bb]; sai += aip[t * B + bb]; }
            float M = (float)(B * ND);
            float f = rsqrtf(str / M + 1e-8f);
            sfac[t] = f; sscl[t] = f * f * sai / M + 1e-6f;
        }
    }
    __syncthreads();

    // j-chunk: inline conv -> global (for topk/final) + packed coeff rows
    if (t < CHUNK) {
        int n = js * CHUNK + t;
        int ci = n / (ND * 5);
        int rem = n % (ND * 5);
        int nd = rem / 5, nk = rem % 5;
        int di = (b * CI + ci) * ND + nd;
        int ki = (co * CI + ci) * 5 + nk;
        float f = sfac[ci], scl = sscl[ci], f2 = f * f;
        float wd = dw[di] / scl;
        float pd0 = f * dp[2 * di], pd1 = f * dp[2 * di + 1];
        float d00, d01, d11;
        if (L0) { d00 = f2 * dc[4 * di]; d01 = f2 * dc[4 * di + 1]; d11 = f2 * dc[4 * di + 3]; }
        else    { d00 = f2 * dc[3 * di]; d01 = f2 * dc[3 * di + 1]; d11 = f2 * dc[3 * di + 2]; }
        float wk = kw[ki], pk0 = kp[2 * ki], pk1 = kp[2 * ki + 1];
        float k00 = kc[4 * ki], k01 = kc[4 * ki + 1], k11 = kc[4 * ki + 3];
        float s00 = d00 + k00, s01 = d01 + k01, s11 = d11 + k11;
        float det_d = d00 * d11 - d01 * d01;
        float det_k = k00 * k11 - k01 * k01;
        float det_s = s00 * s11 - s01 * s01;
        float amp = TWO_PI_F * sqrtf(fmaxf(det_d * det_k / fmaxf(det_s, 1e-12f), 1e-20f));
        float w = wd * wk * amp;
        float q0 = pd0 + pk0, q1 = pd1 + pk1;
        size_t o = base + n;
        cw[o] = w; cp[2 * o] = q0; cp[2 * o + 1] = q1;
        cc[3 * o] = s00; cc[3 * o + 1] = s01; cc[3 * o + 2] = s11;

        float dinv = NHL2E / det_s;
        float A00 = s11 * dinv, A01h = -2.f * s01 * dinv, A11 = s00 * dinv;
        float u0 = -(2.f * A00 * q0 + A01h * q1);
        float u1 = -(A01h * q0 + 2.f * A11 * q1);
        float cj = (A00 * q0 + A01h * q1) * q0 + A11 * q1 * q1;
        float v[6] = {A00, A01h, A11, u0, u1, cj};
        short* row = &sC[t * ROWB];
#pragma unroll
        for (int q = 0; q < 6; ++q) {
            short hs = f2bf(v[q]);
            short ls = f2bf(v[q] - bf2f(hs));
            row[q] = hs; row[6 + q] = ls; row[12 + q] = hs;
        }
#pragma unroll
        for (int q = 18; q < 32; ++q) row[q] = 0;
        sw_[t] = w;
    }

    int lane = t & 63, wave = t >> 6;
    int col = lane & 15, quad = lane >> 4;
    f32x4 sacc[NT];

    for (int sup = 0; sup < NSUP; ++sup) {
        __syncthreads();
        if (t < ISUP) {                       // stage i features
            int i = sup * ISUP + t;
            int ci = i / (ND * 5);
            int rem = i % (ND * 5);
            int nd = rem / 5, nk = rem % 5;
            int di = (b * CI + ci) * ND + nd;
            int ki = (co * CI + ci) * 5 + nk;
            float f = sfac[ci];
            float p0 = f * dp[2 * di] + kp[2 * ki];
            float p1 = f * dp[2 * di + 1] + kp[2 * ki + 1];
            float v[6] = {p0 * p0, p0 * p1, p1 * p1, p0, p1, 1.0f};
            short* row = &sX[t * ROWB];
#pragma unroll
            for (int q = 0; q < 6; ++q) {
                short hs = f2bf(v[q]);
                short ls = f2bf(v[q] - bf2f(hs));
                row[q] = hs; row[6 + q] = hs; row[12 + q] = ls;
            }
#pragma unroll
            for (int q = 18; q < 32; ++q) row[q] = 0;
        }
        __syncthreads();

        s16x8 afr[NT];
#pragma unroll
        for (int n = 0; n < NT; ++n) {
            int it = wave * NT + n;
            afr[n] = *(const s16x8*)&sX[(it * 16 + col) * ROWB + quad * 8];
            sacc[n] = (f32x4){0.f, 0.f, 0.f, 0.f};
        }
        for (int jt = 0; jt < JT; ++jt) {
            s16x8 bfr = *(const s16x8*)&sC[(jt * 16 + col) * ROWB + quad * 8];
            float wv = sw_[jt * 16 + col];
#pragma unroll
            for (int n = 0; n < NT; ++n) {
                f32x4 g = __builtin_amdgcn_mfma_f32_16x16x32_bf16(
                    afr[n], bfr, (f32x4){0.f, 0.f, 0.f, 0.f}, 0, 0, 0);
#pragma unroll
                for (int r = 0; r < 4; ++r)
                    sacc[n][r] = fmaf(wv, __builtin_amdgcn_exp2f(g[r]), sacc[n][r]);
            }
        }
#pragma unroll
        for (int n = 0; n < NT; ++n) {
#pragma unroll
            for (int r = 0; r < 4; ++r) {
                float v = sacc[n][r];
                v += __shfl_xor(v, 1, 64);
                v += __shfl_xor(v, 2, 64);
                v += __shfl_xor(v, 4, 64);
                v += __shfl_xor(v, 8, 64);
                sacc[n][r] = v;
            }
            if (col == 0) {
                int ig = sup * ISUP + (wave * NT + n) * 16 + quad * 4;
                float4 st = make_float4(sacc[n][0], sacc[n][1], sacc[n][2], sacc[n][3]);
                *(float4*)&part[(size_t)js * BLN + base + ig] = st;
            }
        }
    }
}

// ===== topk: relu-finish + iterative argmax (cached local max) + gather =====
__device__ __forceinline__ unsigned int shfl_down_u32(unsigned int v, int off) {
    return (unsigned int)__shfl_down((int)v, off, 64);
}
__global__ __launch_bounds__(256) void topk_kernel(
        const float* __restrict__ part, const float* __restrict__ cw,
        const float* __restrict__ cp, const float* __restrict__ cc,
        float* __restrict__ dw, float* __restrict__ dp, float* __restrict__ dc,
        float* __restrict__ trp, float* __restrict__ aip,
        int N, int K, int BLN, int L) {
    __shared__ unsigned long long skey[1280];
    __shared__ float swn[1280];
    __shared__ unsigned long long wred[4];
    __shared__ unsigned long long bk;
    __shared__ int sel[32];
    int blv = blockIdx.x;
    int b = blv / L, l = blv % L;
    size_t base = (size_t)blv * N;
    int t = threadIdx.x;

    for (int j = t; j < N; j += 256) {
        float s = 0.f;
        for (int q = 0; q < JS; ++q) s += part[(size_t)q * BLN + base + j];
        float denom = (fabsf(s) > 1e-6f) ? s : 1e-6f;
        float wn = cw[base + j] * (fmaxf(s, 0.f) / denom);
        swn[j] = wn;
        float c00 = cc[3 * (base + j)], c01 = cc[3 * (base + j) + 1],
              c11 = cc[3 * (base + j) + 2];
        float det = c00 * c11 - c01 * c01;
        float sc = fabsf(wn) * sqrtf(fmaxf(det, 1e-12f));
        unsigned int ub = __float_as_uint(sc) | 0x80000000u;
        skey[j] = ((unsigned long long)ub << 32) | (unsigned int)(~j);
    }
    __syncthreads();

    unsigned long long mk = 0ull;
    for (int j = t; j < N; j += 256) { unsigned long long v = skey[j]; if (v > mk) mk = v; }

    int lane = t & 63, wid = t >> 6;
    for (int r = 0; r < K; ++r) {
        unsigned int lo = (unsigned int)mk, hi = (unsigned int)(mk >> 32);
        for (int off = 32; off > 0; off >>= 1) {
            unsigned int olo = shfl_down_u32(lo, off);
            unsigned int ohi = shfl_down_u32(hi, off);
            if (ohi > hi || (ohi == hi && olo > lo)) { hi = ohi; lo = olo; }
        }
        if (lane == 0) wred[wid] = ((unsigned long long)hi << 32) | lo;
        __syncthreads();
        if (t == 0) {
            unsigned long long m = wred[0];
            for (int wq = 1; wq < 4; ++wq) if (wred[wq] > m) m = wred[wq];
            sel[r] = (int)(~(unsigned int)m);
            bk = m;
        }
        __syncthreads();
        unsigned long long bkv = bk;
        if (mk == bkv && mk != 0ull) {
            int idx = (int)(~(unsigned int)bkv);
            skey[idx] = 0ull;
            mk = 0ull;
            for (int j = t; j < N; j += 256) { unsigned long long v = skey[j]; if (v > mk) mk = v; }
        }
    }

    float tr_c = 0.f, ai_c = 0.f;
    if (t < K) {
        int idx = sel[t];
        size_t j = base + idx;
        int o = blv * K + t;
        float wn = swn[idx];
        float c00 = cc[3 * j], c01 = cc[3 * j + 1], c11 = cc[3 * j + 2];
        dw[o] = wn;
        dp[2 * o] = cp[2 * j]; dp[2 * o + 1] = cp[2 * j + 1];
        dc[3 * o] = c00; dc[3 * o + 1] = c01; dc[3 * o + 2] = c11;
        tr_c = 0.5f * (c00 + c11);
        float det = c00 * c11 - c01 * c01;
        ai_c = fabsf(wn * TWO_PI_F * sqrtf(fmaxf(det, 1e-12f)));
    }
    if (t < 64) {
        for (int off = 32; off > 0; off >>= 1) {
            tr_c += __shfl_down(tr_c, off, 64);
            ai_c += __shfl_down(ai_c, off, 64);
        }
        if (t == 0) { trp[l * B + b] = tr_c; aip[l * B + b] = ai_c; }
    }
}

// ==== final: per-(b,co) partials; last block does norm + BN + log_softmax ===
__global__ __launch_bounds__(256) void final_kernel(
        const float* __restrict__ part, const float* __restrict__ cw,
        const float* __restrict__ cc,
        float* __restrict__ tbuf, float* __restrict__ ubuf, float* __restrict__ abuf,
        int* __restrict__ cnt, float* __restrict__ out,
        int L, int N, int BLN) {
    int blv = blockIdx.x;
    size_t base = (size_t)blv * N;
    int t = threadIdx.x;
    __shared__ float r1[256], r2[256], r3[256];

    float tsum = 0.f, usum = 0.f, asum = 0.f;
    for (int n = t; n < N; n += 256) {
        size_t o = base + n;
        float c00 = cc[3 * o], c01 = cc[3 * o + 1], c11 = cc[3 * o + 2];
        tsum += 0.5f * (c00 + c11);
        float s = 0.f;
        for (int q = 0; q < JS; ++q) s += part[(size_t)q * BLN + o];
        float denom = (fabsf(s) > 1e-6f) ? s : 1e-6f;
        float wn = cw[o] * (fmaxf(s, 0.f) / denom);
        float det = fmaxf(c00 * c11 - c01 * c01, 1e-30f);
        float integ = wn * TWO_PI_F * sqrtf(det);
        usum += integ;
        asum += fabsf(integ);
    }
    r1[t] = tsum; r2[t] = usum; r3[t] = asum;
    __syncthreads();
    for (int s = 128; s > 0; s >>= 1) {
        if (t < s) { r1[t] += r1[t + s]; r2[t] += r2[t + s]; r3[t] += r3[t + s]; }
        __syncthreads();
    }
    __shared__ int lastf;
    if (t == 0) {
        tbuf[blv] = r1[0]; ubuf[blv] = r2[0]; abuf[blv] = r3[0];
        __threadfence();
        lastf = (atomicAdd(cnt, 1) == (int)gridDim.x - 1);
    }
    __syncthreads();
    if (!lastf) return;
    __threadfence();

    __shared__ float xs[80];
    __shared__ float xn[80];
    if (t < L) {
        float tr = 0.f, a = 0.f;
        for (int bb = 0; bb < B; ++bb) { tr += tbuf[bb * L + t]; a += abuf[bb * L + t]; }
        float m = tr / (float)(B * N);
        float f = rsqrtf(m + 1e-8f);
        float f2 = f * f;
        float scale = f2 * a / (float)(B * N) + 1e-6f;
        for (int bb = 0; bb < B; ++bb) xs[bb * L + t] = f2 * ubuf[bb * L + t] / scale;
    }
    __syncthreads();
    if (t < L) {
        float mu = 0.f;
        for (int bb = 0; bb < B; ++bb) mu += xs[bb * L + t];
        mu *= 0.125f;
        float var = 0.f;
        for (int bb = 0; bb < B; ++bb) { float d = xs[bb * L + t] - mu; var += d * d; }
        var *= 0.125f;
        float inv = rsqrtf(var + 1e-5f);
        for (int bb = 0; bb < B; ++bb) xn[bb * L + t] = (xs[bb * L + t] - mu) * inv;
    }
    __syncthreads();
    if (t < B) {
        float mx = -INFINITY;
        for (int c = 0; c < L; ++c) mx = fmaxf(mx, xn[t * L + c]);
        float se = 0.f;
        for (int c = 0; c < L; ++c) se += expf(xn[t * L + c] - mx);
        float lse = mx + logf(se);
        for (int c = 0; c < L; ++c) out[t * L + c] = xn[t * L + c] - lse;
    }
}

extern "C" void kernel_launch(void* const* d_in, const int* in_sizes, int n_in,
                              void* d_out, int out_size, void* d_ws, size_t ws_size,
                              hipStream_t stream) {
    const float* in_w = (const float*)d_in[0];
    const float* in_p = (const float*)d_in[1];
    const float* in_c = (const float*)d_in[2];
    const float* kw[3] = {(const float*)d_in[3], (const float*)d_in[6], (const float*)d_in[9]};
    const float* kp[3] = {(const float*)d_in[4], (const float*)d_in[7], (const float*)d_in[10]};
    const float* kc[3] = {(const float*)d_in[5], (const float*)d_in[8], (const float*)d_in[11]};

    float* ws   = (float*)d_ws;
    float* dw   = ws + OFF_DW;
    float* dp   = ws + OFF_DP;
    float* dc   = ws + OFF_DC;
    float* cw   = ws + OFF_CW;
    float* cp   = ws + OFF_CP;
    float* cc   = ws + OFF_CC;
    float* partb = ws + OFF_PART;
    float* out  = (float*)d_out;

    float* tail = partb + (size_t)JS * BLN_MAX;
    float* fs0  = tail;          // 8
    float* sc0  = tail + 8;      // 8
    float* trp0 = tail + 16;     // 64
    float* aip0 = tail + 80;     // 64
    float* trp1 = tail + 144;    // 128
    float* aip1 = tail + 272;    // 128
    float* tbuf = tail + 400;    // 80
    float* ubuf = tail + 480;    // 80
    float* abuf = tail + 560;    // 80
    int*   cnt  = (int*)(tail + 640);

    norm0f_kernel<<<B, 128, 0, stream>>>(in_w, in_c, fs0, sc0, cnt);

    // layer 0: Co=8, Ci=1, Nd=128, N=640, K=32
    eval_mfma_kernel<8, 1, 128, true><<<64 * JS, 256, 0, stream>>>(
        in_w, in_p, in_c, kw[0], kp[0], kc[0], fs0, sc0, cw, cp, cc, partb);
    topk_kernel<<<64, 256, 0, stream>>>(partb, cw, cp, cc, dw, dp, dc,
                                        trp0, aip0, 640, 32, 64 * 640, 8);
    // layer 1: Co=16, Ci=8, Nd=32, N=1280, K=16
    eval_mfma_kernel<16, 8, 32, false><<<128 * JS, 256, 0, stream>>>(
        dw, dp, dc, kw[1], kp[1], kc[1], trp0, aip0, cw, cp, cc, partb);
    topk_kernel<<<128, 256, 0, stream>>>(partb, cw, cp, cc, dw, dp, dc,
                                         trp1, aip1, 1280, 16, 128 * 1280, 16);
    // layer 2: Co=10, Ci=16, Nd=16, N=1280, keep all
    eval_mfma_kernel<10, 16, 16, false><<<80 * JS, 256, 0, stream>>>(
        dw, dp, dc, kw[2], kp[2], kc[2], trp1, aip1, cw, cp, cc, partb);
    final_kernel<<<80, 256, 0, stream>>>(partb, cw, cc, tbuf, ubuf, abuf,
                                         cnt, out, 10, 1280, 80 * 1280);
}

// Round 6
// 230.130 us; speedup vs baseline: 1.8881x; 1.0275x over previous
//
#include <hip/hip_runtime.h>
#include <math.h>

#define TWO_PI_F 6.283185307179586f

constexpr int B = 8;

// Workspace layout (floats)
constexpr size_t OFF_DW = 0;        // 2048
constexpr size_t OFF_DP = 2048;     // 4096
constexpr size_t OFF_DC = 6144;     // 6144
constexpr size_t OFF_CW = 12288;    // 163840
constexpr size_t OFF_CP = 176128;   // 327680
constexpr size_t OFF_CC = 503808;   // 491520
constexpr size_t OFF_S  = 995328;   // 163840 (direct s, no partials)
constexpr size_t OFF_T  = 1159168;  // tail scalars

typedef short s16x8 __attribute__((ext_vector_type(8)));
typedef float f32x4 __attribute__((ext_vector_type(4)));

__device__ __forceinline__ short f2bf(float x) {          // RNE fp32->bf16
    unsigned u = __float_as_uint(x);
    return (short)((u + 0x7fffu + ((u >> 16) & 1u)) >> 16);
}
__device__ __forceinline__ float bf2f(short s) {
    return __uint_as_float(((unsigned)(unsigned short)s) << 16);
}

// ============ fused conv + MFMA eval, loop-swapped (direct s) ===============
// block = (bl, i-super of 128). X-rows staged once; j looped in chunks of 128
// with inline conv+pack. g = x.c via bf16 hi/lo split, 24 of K=32 slots:
// X = [xh,xl,xh,xl] grouping, C = [ch,ch,cl,cl] -> (xh+xl)(ch+cl) exact.
template <int CO, int CI, int ND, bool L0>
__global__ __launch_bounds__(256) void eval_mfma_kernel(
        const float* __restrict__ dw, const float* __restrict__ dp,
        const float* __restrict__ dc,
        const float* __restrict__ kw, const float* __restrict__ kp,
        const float* __restrict__ kc,
        const float* __restrict__ trp, const float* __restrict__ aip,
        float* __restrict__ cw, float* __restrict__ cp, float* __restrict__ cc,
        float* __restrict__ sbuf, int* __restrict__ cnt) {
    constexpr int N    = CI * ND * 5;
    constexpr int NSUP = N / 128;
    constexpr int NCH  = N / 128;
    constexpr int FAC  = (CI < 2) ? 2 : CI;

    __shared__ __align__(16) short sX[128 * 32];
    __shared__ __align__(16) short sC[128 * 32];
    __shared__ float sw_[128];
    __shared__ float sfac[FAC], sscl[FAC];
    __shared__ float red[128];

    int blk = blockIdx.x;
    int sup = blk % NSUP;
    int bl  = blk / NSUP;                 // b*CO + co
    int b = bl / CO, co = bl % CO;
    int t = threadIdx.x;
    size_t base = (size_t)bl * N;
    const float NHL2E = -0.72134752044448f;   // -0.5*log2(e)

    if (L0 && blk == 0 && t == 0) *cnt = 0;

    // ---- phase A: per-channel norm factors ----
    if (L0) {
        float w0 = 0.f, c00 = 0.f, c01 = 0.f, c11 = 0.f;
        if (t < 128) {
            int idx = b * 128 + t;
            w0 = dw[idx];
            c00 = dc[4 * idx]; c01 = dc[4 * idx + 1]; c11 = dc[4 * idx + 3];
        }
        if (t < 128) red[t] = 0.5f * (c00 + c11);
        __syncthreads();
        for (int s = 64; s > 0; s >>= 1) {
            if (t < s) red[t] += red[t + s];
            __syncthreads();
        }
        float f = rsqrtf(red[0] / 128.f + 1e-8f);
        __syncthreads();
        float f2 = f * f;
        float det = (c00 * c11 - c01 * c01) * f2 * f2;
        if (t < 128) red[t] = fabsf(w0 * TWO_PI_F * sqrtf(fmaxf(det, 1e-12f)));
        __syncthreads();
        for (int s = 64; s > 0; s >>= 1) {
            if (t < s) red[t] += red[t + s];
            __syncthreads();
        }
        if (t == 0) { sfac[0] = f; sscl[0] = red[0] / 128.f + 1e-6f; }
    } else {
        if (t < CI) {
            float str = 0.f, sai = 0.f;
            for (int bb = 0; bb < B; ++bb) { str += trp[t * B + bb]; sai += aip[t * B + bb]; }
            float M = (float)(B * ND);
            float f = rsqrtf(str / M + 1e-8f);
            sfac[t] = f; sscl[t] = f * f * sai / M + 1e-6f;
        }
    }
    __syncthreads();

    // ---- phase B: stage 128 X-rows (positions) once ----
    if (t < 128) {
        int i = sup * 128 + t;
        int ci = i / (ND * 5);
        int rem = i % (ND * 5);
        int nd = rem / 5, nk = rem % 5;
        int di = (b * CI + ci) * ND + nd;
        int ki = (co * CI + ci) * 5 + nk;
        float f = sfac[ci];
        float p0 = f * dp[2 * di] + kp[2 * ki];
        float p1 = f * dp[2 * di + 1] + kp[2 * ki + 1];
        float v[6] = {p0 * p0, p0 * p1, p1 * p1, p0, p1, 1.0f};
        short h[6], l[6];
#pragma unroll
        for (int q = 0; q < 6; ++q) {
            h[q] = f2bf(v[q]);
            l[q] = f2bf(v[q] - bf2f(h[q]));
        }
        // slots: [h0..5, l0..5, h0..5, l0..5, 0 x8]
        s16x8 r0, r1, r2, r3;
        r0[0]=h[0]; r0[1]=h[1]; r0[2]=h[2]; r0[3]=h[3]; r0[4]=h[4]; r0[5]=h[5]; r0[6]=l[0]; r0[7]=l[1];
        r1[0]=l[2]; r1[1]=l[3]; r1[2]=l[4]; r1[3]=l[5]; r1[4]=h[0]; r1[5]=h[1]; r1[6]=h[2]; r1[7]=h[3];
        r2[0]=h[4]; r2[1]=h[5]; r2[2]=l[0]; r2[3]=l[1]; r2[4]=l[2]; r2[5]=l[3]; r2[6]=l[4]; r2[7]=l[5];
        r3 = (s16x8){0,0,0,0,0,0,0,0};
        s16x8* row = (s16x8*)&sX[t * 32];
        row[0] = r0; row[1] = r1; row[2] = r2; row[3] = r3;
    }
    __syncthreads();

    int lane = t & 63, wave = t >> 6;
    int col = lane & 15, quad = lane >> 4;
    s16x8 afr[2];
    f32x4 sacc[2];
#pragma unroll
    for (int n = 0; n < 2; ++n) {
        int it = wave * 2 + n;
        afr[n] = *(const s16x8*)&sX[((it * 16 + col) * 32) + quad * 8];
        sacc[n] = (f32x4){0.f, 0.f, 0.f, 0.f};
    }

    // ---- j chunks: inline conv + pack, then MFMA+exp2 ----
    for (int ch = 0; ch < NCH; ++ch) {
        __syncthreads();           // protect sC from previous inner reads
        if (t < 128) {
            int n = ch * 128 + t;
            int ci = n / (ND * 5);
            int rem = n % (ND * 5);
            int nd = rem / 5, nk = rem % 5;
            int di = (b * CI + ci) * ND + nd;
            int ki = (co * CI + ci) * 5 + nk;
            float f = sfac[ci], scl = sscl[ci], f2 = f * f;
            float wd = dw[di] / scl;
            float pd0 = f * dp[2 * di], pd1 = f * dp[2 * di + 1];
            float d00, d01, d11;
            if (L0) { d00 = f2 * dc[4 * di]; d01 = f2 * dc[4 * di + 1]; d11 = f2 * dc[4 * di + 3]; }
            else    { d00 = f2 * dc[3 * di]; d01 = f2 * dc[3 * di + 1]; d11 = f2 * dc[3 * di + 2]; }
            float wk = kw[ki], pk0 = kp[2 * ki], pk1 = kp[2 * ki + 1];
            float k00 = kc[4 * ki], k01 = kc[4 * ki + 1], k11 = kc[4 * ki + 3];
            float s00 = d00 + k00, s01 = d01 + k01, s11 = d11 + k11;
            float det_d = d00 * d11 - d01 * d01;
            float det_k = k00 * k11 - k01 * k01;
            float det_s = s00 * s11 - s01 * s01;
            float amp = TWO_PI_F * sqrtf(fmaxf(det_d * det_k / fmaxf(det_s, 1e-12f), 1e-20f));
            float w = wd * wk * amp;
            float q0 = pd0 + pk0, q1 = pd1 + pk1;
            if (sup == 0) {
                size_t o = base + n;
                cw[o] = w; cp[2 * o] = q0; cp[2 * o + 1] = q1;
                cc[3 * o] = s00; cc[3 * o + 1] = s01; cc[3 * o + 2] = s11;
            }
            float dinv = NHL2E / det_s;
            float A00 = s11 * dinv, A01h = -2.f * s01 * dinv, A11 = s00 * dinv;
            float u0 = -(2.f * A00 * q0 + A01h * q1);
            float u1 = -(A01h * q0 + 2.f * A11 * q1);
            float cj = (A00 * q0 + A01h * q1) * q0 + A11 * q1 * q1;
            float v[6] = {A00, A01h, A11, u0, u1, cj};
            short h[6], l[6];
#pragma unroll
            for (int q = 0; q < 6; ++q) {
                h[q] = f2bf(v[q]);
                l[q] = f2bf(v[q] - bf2f(h[q]));
            }
            // slots: [ch0..5, ch0..5, cl0..5, cl0..5, 0 x8]
            s16x8 r0, r1, r2, r3;
            r0[0]=h[0]; r0[1]=h[1]; r0[2]=h[2]; r0[3]=h[3]; r0[4]=h[4]; r0[5]=h[5]; r0[6]=h[0]; r0[7]=h[1];
            r1[0]=h[2]; r1[1]=h[3]; r1[2]=h[4]; r1[3]=h[5]; r1[4]=l[0]; r1[5]=l[1]; r1[6]=l[2]; r1[7]=l[3];
            r2[0]=l[4]; r2[1]=l[5]; r2[2]=l[0]; r2[3]=l[1]; r2[4]=l[2]; r2[5]=l[3]; r2[6]=l[4]; r2[7]=l[5];
            r3 = (s16x8){0,0,0,0,0,0,0,0};
            s16x8* row = (s16x8*)&sC[t * 32];
            row[0] = r0; row[1] = r1; row[2] = r2; row[3] = r3;
            sw_[t] = w;
        }
        __syncthreads();

#pragma unroll
        for (int jt = 0; jt < 8; ++jt) {
            s16x8 bfr = *(const s16x8*)&sC[((jt * 16 + col) * 32) + quad * 8];
            float wv = sw_[jt * 16 + col];
#pragma unroll
            for (int n = 0; n < 2; ++n) {
                f32x4 g = __builtin_amdgcn_mfma_f32_16x16x32_bf16(
                    afr[n], bfr, (f32x4){0.f, 0.f, 0.f, 0.f}, 0, 0, 0);
#pragma unroll
                for (int r = 0; r < 4; ++r)
                    sacc[n][r] = fmaf(wv, __builtin_amdgcn_exp2f(g[r]), sacc[n][r]);
            }
        }
    }

    // ---- reduce over 16 cols (j) and store s ----
#pragma unroll
    for (int n = 0; n < 2; ++n) {
#pragma unroll
        for (int r = 0; r < 4; ++r) {
            float v = sacc[n][r];
            v += __shfl_xor(v, 1, 64);
            v += __shfl_xor(v, 2, 64);
            v += __shfl_xor(v, 4, 64);
            v += __shfl_xor(v, 8, 64);
            sacc[n][r] = v;
        }
        if (col == 0) {
            int ig = sup * 128 + (wave * 2 + n) * 16 + quad * 4;
            float4 st = make_float4(sacc[n][0], sacc[n][1], sacc[n][2], sacc[n][3]);
            *(float4*)&sbuf[base + ig] = st;
        }
    }
}

// ===== topk: relu-finish + iterative argmax (cached local max) + gather =====
__device__ __forceinline__ unsigned int shfl_down_u32(unsigned int v, int off) {
    return (unsigned int)__shfl_down((int)v, off, 64);
}
__global__ __launch_bounds__(256) void topk_kernel(
        const float* __restrict__ sbuf, const float* __restrict__ cw,
        const float* __restrict__ cp, const float* __restrict__ cc,
        float* __restrict__ dw, float* __restrict__ dp, float* __restrict__ dc,
        float* __restrict__ trp, float* __restrict__ aip,
        int N, int K, int L) {
    __shared__ unsigned long long skey[1280];
    __shared__ float swn[1280];
    __shared__ unsigned long long wred[4];
    __shared__ unsigned long long bk;
    __shared__ int sel[32];
    int blv = blockIdx.x;
    int b = blv / L, l = blv % L;
    size_t base = (size_t)blv * N;
    int t = threadIdx.x;

    for (int j = t; j < N; j += 256) {
        float s = sbuf[base + j];
        float denom = (fabsf(s) > 1e-6f) ? s : 1e-6f;
        float wn = cw[base + j] * (fmaxf(s, 0.f) / denom);
        swn[j] = wn;
        float c00 = cc[3 * (base + j)], c01 = cc[3 * (base + j) + 1],
              c11 = cc[3 * (base + j) + 2];
        float det = c00 * c11 - c01 * c01;
        float sc = fabsf(wn) * sqrtf(fmaxf(det, 1e-12f));
        unsigned int ub = __float_as_uint(sc) | 0x80000000u;
        skey[j] = ((unsigned long long)ub << 32) | (unsigned int)(~j);
    }
    __syncthreads();

    unsigned long long mk = 0ull;
    for (int j = t; j < N; j += 256) { unsigned long long v = skey[j]; if (v > mk) mk = v; }

    int lane = t & 63, wid = t >> 6;
    for (int r = 0; r < K; ++r) {
        unsigned int lo = (unsigned int)mk, hi = (unsigned int)(mk >> 32);
        for (int off = 32; off > 0; off >>= 1) {
            unsigned int olo = shfl_down_u32(lo, off);
            unsigned int ohi = shfl_down_u32(hi, off);
            if (ohi > hi || (ohi == hi && olo > lo)) { hi = ohi; lo = olo; }
        }
        if (lane == 0) wred[wid] = ((unsigned long long)hi << 32) | lo;
        __syncthreads();
        if (t == 0) {
            unsigned long long m = wred[0];
            for (int wq = 1; wq < 4; ++wq) if (wred[wq] > m) m = wred[wq];
            sel[r] = (int)(~(unsigned int)m);
            bk = m;
        }
        __syncthreads();
        unsigned long long bkv = bk;
        if (mk == bkv && mk != 0ull) {
            int idx = (int)(~(unsigned int)bkv);
            skey[idx] = 0ull;
            mk = 0ull;
            for (int j = t; j < N; j += 256) { unsigned long long v = skey[j]; if (v > mk) mk = v; }
        }
    }

    float tr_c = 0.f, ai_c = 0.f;
    if (t < K) {
        int idx = sel[t];
        size_t j = base + idx;
        int o = blv * K + t;
        float wn = swn[idx];
        float c00 = cc[3 * j], c01 = cc[3 * j + 1], c11 = cc[3 * j + 2];
        dw[o] = wn;
        dp[2 * o] = cp[2 * j]; dp[2 * o + 1] = cp[2 * j + 1];
        dc[3 * o] = c00; dc[3 * o + 1] = c01; dc[3 * o + 2] = c11;
        tr_c = 0.5f * (c00 + c11);
        float det = c00 * c11 - c01 * c01;
        ai_c = fabsf(wn * TWO_PI_F * sqrtf(fmaxf(det, 1e-12f)));
    }
    if (t < 64) {
        for (int off = 32; off > 0; off >>= 1) {
            tr_c += __shfl_down(tr_c, off, 64);
            ai_c += __shfl_down(ai_c, off, 64);
        }
        if (t == 0) { trp[l * B + b] = tr_c; aip[l * B + b] = ai_c; }
    }
}

// ==== final: per-(b,co) partials; last block does norm + BN + log_softmax ===
__global__ __launch_bounds__(256) void final_kernel(
        const float* __restrict__ sbuf, const float* __restrict__ cw,
        const float* __restrict__ cc,
        float* __restrict__ tbuf, float* __restrict__ ubuf, float* __restrict__ abuf,
        int* __restrict__ cnt, float* __restrict__ out,
        int L, int N) {
    int blv = blockIdx.x;
    size_t base = (size_t)blv * N;
    int t = threadIdx.x;
    __shared__ float r1[256], r2[256], r3[256];

    float tsum = 0.f, usum = 0.f, asum = 0.f;
    for (int n = t; n < N; n += 256) {
        size_t o = base + n;
        float c00 = cc[3 * o], c01 = cc[3 * o + 1], c11 = cc[3 * o + 2];
        tsum += 0.5f * (c00 + c11);
        float s = sbuf[o];
        float denom = (fabsf(s) > 1e-6f) ? s : 1e-6f;
        float wn = cw[o] * (fmaxf(s, 0.f) / denom);
        float det = fmaxf(c00 * c11 - c01 * c01, 1e-30f);
        float integ = wn * TWO_PI_F * sqrtf(det);
        usum += integ;
        asum += fabsf(integ);
    }
    r1[t] = tsum; r2[t] = usum; r3[t] = asum;
    __syncthreads();
    for (int s = 128; s > 0; s >>= 1) {
        if (t < s) { r1[t] += r1[t + s]; r2[t] += r2[t + s]; r3[t] += r3[t + s]; }
        __syncthreads();
    }
    __shared__ int lastf;
    if (t == 0) {
        tbuf[blv] = r1[0]; ubuf[blv] = r2[0]; abuf[blv] = r3[0];
        __threadfence();
        lastf = (atomicAdd(cnt, 1) == (int)gridDim.x - 1);
    }
    __syncthreads();
    if (!lastf) return;
    __threadfence();

    __shared__ float xs[80];
    __shared__ float xn[80];
    if (t < L) {
        float tr = 0.f, a = 0.f;
        for (int bb = 0; bb < B; ++bb) { tr += tbuf[bb * L + t]; a += abuf[bb * L + t]; }
        float m = tr / (float)(B * N);
        float f = rsqrtf(m + 1e-8f);
        float f2 = f * f;
        float scale = f2 * a / (float)(B * N) + 1e-6f;
        for (int bb = 0; bb < B; ++bb) xs[bb * L + t] = f2 * ubuf[bb * L + t] / scale;
    }
    __syncthreads();
    if (t < L) {
        float mu = 0.f;
        for (int bb = 0; bb < B; ++bb) mu += xs[bb * L + t];
        mu *= 0.125f;
        float var = 0.f;
        for (int bb = 0; bb < B; ++bb) { float d = xs[bb * L + t] - mu; var += d * d; }
        var *= 0.125f;
        float inv = rsqrtf(var + 1e-5f);
        for (int bb = 0; bb < B; ++bb) xn[bb * L + t] = (xs[bb * L + t] - mu) * inv;
    }
    __syncthreads();
    if (t < B) {
        float mx = -INFINITY;
        for (int c = 0; c < L; ++c) mx = fmaxf(mx, xn[t * L + c]);
        float se = 0.f;
        for (int c = 0; c < L; ++c) se += expf(xn[t * L + c] - mx);
        float lse = mx + logf(se);
        for (int c = 0; c < L; ++c) out[t * L + c] = xn[t * L + c] - lse;
    }
}

extern "C" void kernel_launch(void* const* d_in, const int* in_sizes, int n_in,
                              void* d_out, int out_size, void* d_ws, size_t ws_size,
                              hipStream_t stream) {
    const float* in_w = (const float*)d_in[0];
    const float* in_p = (const float*)d_in[1];
    const float* in_c = (const float*)d_in[2];
    const float* kw[3] = {(const float*)d_in[3], (const float*)d_in[6], (const float*)d_in[9]};
    const float* kp[3] = {(const float*)d_in[4], (const float*)d_in[7], (const float*)d_in[10]};
    const float* kc[3] = {(const float*)d_in[5], (const float*)d_in[8], (const float*)d_in[11]};

    float* ws  = (float*)d_ws;
    float* dw  = ws + OFF_DW;
    float* dp  = ws + OFF_DP;
    float* dc  = ws + OFF_DC;
    float* cw  = ws + OFF_CW;
    float* cp  = ws + OFF_CP;
    float* cc  = ws + OFF_CC;
    float* sb  = ws + OFF_S;
    float* out = (float*)d_out;

    float* tail = ws + OFF_T;
    float* trp0 = tail;          // 64
    float* aip0 = tail + 64;     // 64
    float* trp1 = tail + 128;    // 128
    float* aip1 = tail + 256;    // 128
    float* tbuf = tail + 384;    // 80
    float* ubuf = tail + 464;    // 80
    float* abuf = tail + 544;    // 80
    int*   cnt  = (int*)(tail + 624);

    // layer 0: Co=8, Ci=1, Nd=128, N=640, K=32 (norm0 fused, resets cnt)
    eval_mfma_kernel<8, 1, 128, true><<<8 * 8 * 5, 256, 0, stream>>>(
        in_w, in_p, in_c, kw[0], kp[0], kc[0], nullptr, nullptr,
        cw, cp, cc, sb, cnt);
    topk_kernel<<<64, 256, 0, stream>>>(sb, cw, cp, cc, dw, dp, dc,
                                        trp0, aip0, 640, 32, 8);
    // layer 1: Co=16, Ci=8, Nd=32, N=1280, K=16
    eval_mfma_kernel<16, 8, 32, false><<<8 * 16 * 10, 256, 0, stream>>>(
        dw, dp, dc, kw[1], kp[1], kc[1], trp0, aip0, cw, cp, cc, sb, cnt);
    topk_kernel<<<128, 256, 0, stream>>>(sb, cw, cp, cc, dw, dp, dc,
                                         trp1, aip1, 1280, 16, 16);
    // layer 2: Co=10, Ci=16, Nd=16, N=1280, keep all
    eval_mfma_kernel<10, 16, 16, false><<<8 * 10 * 10, 256, 0, stream>>>(
        dw, dp, dc, kw[2], kp[2], kc[2], trp1, aip1, cw, cp, cc, sb, cnt);
    final_kernel<<<80, 256, 0, stream>>>(sb, cw, cc, tbuf, ubuf, abuf,
                                         cnt, out, 10, 1280);
}